// Round 10
// baseline (594.248 us; speedup 1.0000x reference)
//
#include <hip/hip_runtime.h>

#define NN 40000
#define DDEG 16
#define FF 128
#define OO 128
#define NG 512   // 4*F gates
#define XIH_ELEMS 20480000   // NN*NG u16 per relation
#define L2E 1.4426950408889634f
#define TWO_L2E 2.8853900817779268f

typedef short  s16x8 __attribute__((ext_vector_type(8)));
typedef unsigned short u16x8 __attribute__((ext_vector_type(8)));
typedef unsigned short u16x4 __attribute__((ext_vector_type(4)));
typedef float  f32x4 __attribute__((ext_vector_type(4)));

static_assert(sizeof(s16x8) == 16, "frag size");

__device__ __forceinline__ unsigned short f2bf(float f) {
    unsigned int u = __builtin_bit_cast(unsigned int, f);
    u += 0x7FFFu + ((u >> 16) & 1u);   // RNE
    return (unsigned short)(u >> 16);
}
__device__ __forceinline__ float bf2f(unsigned short s) {
    unsigned int u = ((unsigned int)s) << 16;
    return __builtin_bit_cast(float, u);
}
__device__ __forceinline__ f32x4 splat4(float v) { f32x4 r = {v, v, v, v}; return r; }

// ---- prep: weights -> bf16 with exp2 prescale; Ws/Wn transpose; feat cast ----
// gate-row scale: rows [0,256)+[384,512) (i,f,o): log2e; rows [256,384) (g): 2*log2e
__global__ void k_prep(const float* __restrict__ Wih, const float* __restrict__ Whh,
                       const float* __restrict__ Ws,  const float* __restrict__ Wn,
                       const float* __restrict__ feat,
                       unsigned short* __restrict__ wihb, unsigned short* __restrict__ whhb,
                       unsigned short* __restrict__ wstb, unsigned short* __restrict__ wntb,
                       unsigned short* __restrict__ fbf) {
    int i = blockIdx.x * blockDim.x + threadIdx.x;
    int stride = gridDim.x * blockDim.x;
    for (int idx = i; idx < 4 * NG * FF; idx += stride) {
        int row = (idx >> 7) & 511;
        float s = ((row >> 7) == 2) ? TWO_L2E : L2E;
        wihb[idx] = f2bf(Wih[idx] * s);
        whhb[idx] = f2bf(Whh[idx] * s);
    }
    for (int idx = i; idx < 4 * FF * OO; idx += stride) {
        int r = idx >> 14;
        int rem = idx & 16383;
        int o = rem >> 7;
        int k = rem & 127;
        wstb[idx] = f2bf(Ws[(r << 14) + (k << 7) + o]);
        wntb[idx] = f2bf(Wn[(r << 14) + (k << 7) + o]);
    }
    for (int idx4 = i * 4; idx4 < NN * FF; idx4 += stride * 4) {
        float4 v = *(const float4*)(feat + idx4);
        ushort4 o;
        o.x = f2bf(v.x); o.y = f2bf(v.y); o.z = f2bf(v.z); o.w = f2bf(v.w);
        *(ushort4*)(fbf + idx4) = o;
    }
}

// ---------------- segment mean (seg_ids sorted, G=64), float4 vectorized -----
__global__ void k_segmean(const float* __restrict__ feat, const int* __restrict__ seg,
                          float* __restrict__ mean) {
    int g = blockIdx.x;
    int lo, hi;
    { int a = 0, b = NN; while (a < b) { int m = (a + b) >> 1; if (seg[m] < g) a = m + 1; else b = m; } lo = a; }
    { int a = 0, b = NN; while (a < b) { int m = (a + b) >> 1; if (seg[m] < g + 1) a = m + 1; else b = m; } hi = a; }
    int tid = threadIdx.x;
    int d4 = tid & 31;
    int part = tid >> 5;
    float4 s = {0.f, 0.f, 0.f, 0.f};
    for (int row = lo + part; row < hi; row += 8) {
        float4 v = *(const float4*)(feat + (size_t)row * FF + d4 * 4);
        s.x += v.x; s.y += v.y; s.z += v.z; s.w += v.w;
    }
    __shared__ float ps[8][128];
    ps[part][d4 * 4 + 0] = s.x; ps[part][d4 * 4 + 1] = s.y;
    ps[part][d4 * 4 + 2] = s.z; ps[part][d4 * 4 + 3] = s.w;
    __syncthreads();
    if (tid < 128) {
        float tot = 0.f;
#pragma unroll
        for (int p = 0; p < 8; ++p) tot += ps[p][tid];
        mean[g * FF + tid] = tot / fmaxf((float)(hi - lo), 1.0f);
    }
}

// ---------------- deg bucketing, all 4 relations (two-level histogram) -------
__global__ void k_count(const int* __restrict__ D0, const int* __restrict__ D1,
                        const int* __restrict__ D2, const int* __restrict__ D3,
                        int* __restrict__ cnt4) {
    int r = blockIdx.y;
    const int* dg = (r == 0) ? D0 : (r == 1) ? D1 : (r == 2) ? D2 : D3;
    __shared__ int lcnt[17];
    if (threadIdx.x < 17) lcnt[threadIdx.x] = 0;
    __syncthreads();
    int n = blockIdx.x * blockDim.x + threadIdx.x;
    if (n < NN) { int d = dg[n]; if (d > 0) atomicAdd(&lcnt[d], 1); }
    __syncthreads();
    if (threadIdx.x >= 1 && threadIdx.x < 17 && lcnt[threadIdx.x])
        atomicAdd(&cnt4[r * 64 + threadIdx.x], lcnt[threadIdx.x]);
}
__global__ void k_offsets(int* __restrict__ cnt4) {
    int r = threadIdx.x;
    if (r < 4 && blockIdx.x == 0) {
        int running = 0;
        for (int d = 16; d >= 1; --d) {
            cnt4[r * 64 + 40 + d] = running;
            running += (cnt4[r * 64 + d] + 15) & ~15;
        }
    }
}
__global__ void k_scatter(const int* __restrict__ D0, const int* __restrict__ D1,
                          const int* __restrict__ D2, const int* __restrict__ D3,
                          int* __restrict__ cnt4, int* __restrict__ order4) {
    int r = blockIdx.y;
    const int* dg = (r == 0) ? D0 : (r == 1) ? D1 : (r == 2) ? D2 : D3;
    __shared__ int lcnt[17];
    __shared__ int gbase[17];
    if (threadIdx.x < 17) lcnt[threadIdx.x] = 0;
    __syncthreads();
    int n = blockIdx.x * blockDim.x + threadIdx.x;
    int d = 0, rank = 0;
    if (n < NN) { d = dg[n]; if (d > 0) rank = atomicAdd(&lcnt[d], 1); }
    __syncthreads();
    if (threadIdx.x >= 1 && threadIdx.x < 17 && lcnt[threadIdx.x])
        gbase[threadIdx.x] = atomicAdd(&cnt4[r * 64 + 40 + threadIdx.x], lcnt[threadIdx.x]);
    __syncthreads();
    if (n < NN && d > 0) order4[r * 40960 + gbase[d] + rank] = n;
}

// ---------------- Xih = feat @ Wih[r].T + b(scaled), 8-wave-permuted layout --
// u16 index in 512-row: (T&7)*64 + col*4 + (T>>3) for gate-tile T.
// 32 nodes/block (2 A-sets amortize each B-frag); 4 waves, tiles {w+4j}.
__global__ __launch_bounds__(256, 4) void k_xih(const unsigned short* __restrict__ fbf,
                                                const unsigned short* __restrict__ wihb,
                                                const float* __restrict__ lb,
                                                unsigned short* __restrict__ xih, int rbase) {
    int r = rbase + blockIdx.y;
    unsigned short* xr = xih + (size_t)blockIdx.y * XIH_ELEMS;
    int tid = threadIdx.x;
    int w = tid >> 6;
    int l = tid & 63;
    int n0 = blockIdx.x * 32;
    int col = l & 15, grp = l >> 4;

    f32x4 acc[8][2];
#pragma unroll
    for (int j = 0; j < 8; ++j) {
        float sc = (((w + 4 * j) >> 3) == 2) ? TWO_L2E : L2E;
        f32x4 b = splat4(lb[r * NG + (w + 4 * j) * 16 + col] * sc);
        acc[j][0] = b; acc[j][1] = b;
    }

    s16x8 a0[4], a1[4];
    const unsigned short* ap0 = fbf + (size_t)(n0 + col) * FF + grp * 8;
    const unsigned short* ap1 = fbf + (size_t)(n0 + 16 + col) * FF + grp * 8;
#pragma unroll
    for (int kt = 0; kt < 4; ++kt) {
        a0[kt] = *(const s16x8*)(ap0 + kt * 32);
        a1[kt] = *(const s16x8*)(ap1 + kt * 32);
    }

    const unsigned short* wb = wihb + (size_t)r * NG * FF + col * FF + grp * 8;
#pragma unroll
    for (int j = 0; j < 8; ++j) {
#pragma unroll
        for (int kt = 0; kt < 4; ++kt) {
            s16x8 b = *(const s16x8*)(wb + (size_t)(w + 4 * j) * 16 * FF + kt * 32);
            acc[j][0] = __builtin_amdgcn_mfma_f32_16x16x32_bf16(a0[kt], b, acc[j][0], 0, 0, 0);
            acc[j][1] = __builtin_amdgcn_mfma_f32_16x16x32_bf16(a1[kt], b, acc[j][1], 0, 0, 0);
        }
    }
    // store: tile T=w+4j -> u16 idx (T&7)*64+col*4+(T>>3); j even -> slot w, j odd -> slot w+4
#pragma unroll
    for (int s = 0; s < 2; ++s) {
#pragma unroll
        for (int q = 0; q < 4; ++q) {
            int node = n0 + s * 16 + grp * 4 + q;
            u16x4 ue, uo;
#pragma unroll
            for (int m = 0; m < 4; ++m) {
                ue[m] = f2bf(acc[2 * m][s][q]);
                uo[m] = f2bf(acc[2 * m + 1][s][q]);
            }
            *(u16x4*)(xr + (size_t)node * NG + w * 64 + col * 4) = ue;
            *(u16x4*)(xr + (size_t)node * NG + (w + 4) * 64 + col * 4) = uo;
        }
    }
}

// ---------------- bucketed LSTM: 8 waves x 4 tiles, depth-2 gather prefetch --
// 512 thr; wave w owns tiles {w+8j}; i/f/g/o quadruple thread-local; t-loop
// unrolled x2 with ping-pong buffers: loads for t+2 issued while computing t
// (~2 steps of latency coverage for the L3-resident xih gather).
#define LSTM_BLOCKS 1280
#define LSTM_GROUPS 2
__global__ __launch_bounds__(512, 4) void k_lstm(const unsigned short* __restrict__ xih,
                                                 const unsigned short* __restrict__ whhb,
                                                 const int* __restrict__ order4,
                                                 const int* __restrict__ N0, const int* __restrict__ N1,
                                                 const int* __restrict__ N2, const int* __restrict__ N3,
                                                 const int* __restrict__ D0, const int* __restrict__ D1,
                                                 const int* __restrict__ D2, const int* __restrict__ D3,
                                                 unsigned short* __restrict__ hfin4, int rbase) {
    int r = rbase + blockIdx.y;
    const unsigned short* xr = xih + (size_t)blockIdx.y * XIH_ELEMS;
    const int* nbr = (r == 0) ? N0 : (r == 1) ? N1 : (r == 2) ? N2 : N3;
    const int* deg = (r == 0) ? D0 : (r == 1) ? D1 : (r == 2) ? D2 : D3;
    const int* order = order4 + r * 40960;
    unsigned short* hfin = hfin4 + (size_t)r * NN * FF;

    __shared__ int nodes[16];
    __shared__ int nbrs[16][16];               // premultiplied byte offsets (node*1024)
    __shared__ unsigned short hbuf[2][2048];   // 2 x (16 rows x 128 dims bf16), XOR-swizzled
    int tid = threadIdx.x;
    int w = tid >> 6, l = tid & 63;
    int col = l & 15, grp = l >> 4;

    // Whh slice: tiles {w+8j}, 16 frags = 64 regs
    const unsigned short* whhp = whhb + (size_t)r * NG * FF + col * FF + grp * 8;
    s16x8 breg[4][4];
#pragma unroll
    for (int j = 0; j < 4; ++j)
#pragma unroll
        for (int kt = 0; kt < 4; ++kt)
            breg[j][kt] = *(const s16x8*)(whhp + (size_t)(w + 8 * j) * 16 * FF + kt * 32);

    const char* xbc = (const char*)(xr + w * 64 + col * 4);

    int rbyte[4];
#pragma unroll
    for (int kt = 0; kt < 4; ++kt)
        rbyte[kt] = (col * 256 + kt * 64 + grp * 16) ^ ((col & 7) << 4);
    int wbyte[4];
#pragma unroll
    for (int q = 0; q < 4; ++q) {
        int node = grp * 4 + q;
        wbyte[q] = (node * 256 + (w * 16 + col) * 2) ^ ((node & 7) << 4);
    }

    for (int gi = 0; gi < LSTM_GROUPS; ++gi) {
        int g0 = (blockIdx.x + gi * LSTM_BLOCKS) * 16;
        __syncthreads();
        if (tid < 16) nodes[tid] = order[g0 + tid];
        __syncthreads();
        if (nodes[0] < 0) continue;          // uniform
        int degv = deg[nodes[0]];

        if (tid < 256) {
            int row = tid >> 4, t = tid & 15;
            int nd = nodes[row]; if (nd < 0) nd = 0;
            nbrs[row][t] = nbr[nd * DDEG + t] << 10;
        }
        __syncthreads();

        float cst[4];
#pragma unroll
        for (int e = 0; e < 4; ++e) cst[e] = 0.f;

        // ping-pong prefetch buffers: bufA = even steps, bufB = odd steps
        u16x4 bufA[4], bufB[4];
#pragma unroll
        for (int q = 0; q < 4; ++q)
            bufA[q] = *(const u16x4*)(xbc + (unsigned)nbrs[grp * 4 + q][0]);
        if (degv > 1) {
#pragma unroll
            for (int q = 0; q < 4; ++q)
                bufB[q] = *(const u16x4*)(xbc + (unsigned)nbrs[grp * 4 + q][1]);
        }

        // one LSTM step: consume BUF (data for step T), refill BUF for T+2
#define LSTM_STEP(BUF, T)                                                               \
        {                                                                               \
            f32x4 acc[4];                                                               \
            _Pragma("unroll")                                                           \
            for (int j = 0; j < 4; ++j)                                                 \
                _Pragma("unroll")                                                       \
                for (int q = 0; q < 4; ++q)                                             \
                    acc[j][q] = bf2f(BUF[q][j]);                                        \
            if ((T) + 2 < degv) {                                                       \
                _Pragma("unroll")                                                       \
                for (int q = 0; q < 4; ++q)                                             \
                    BUF[q] = *(const u16x4*)(xbc + (unsigned)nbrs[grp * 4 + q][(T) + 2]); \
            }                                                                           \
            if ((T) > 0) {                                                              \
                const char* hrd = (const char*)hbuf[(T) & 1];                           \
                _Pragma("unroll")                                                       \
                for (int kt = 0; kt < 4; ++kt) {                                        \
                    s16x8 ah = *(const s16x8*)(hrd + rbyte[kt]);                        \
                    _Pragma("unroll")                                                   \
                    for (int j = 0; j < 4; ++j)                                         \
                        acc[j] = __builtin_amdgcn_mfma_f32_16x16x32_bf16(ah, breg[j][kt], acc[j], 0, 0, 0); \
                }                                                                       \
            }                                                                           \
            char* hwr = (char*)hbuf[((T) + 1) & 1];                                     \
            _Pragma("unroll")                                                           \
            for (int q = 0; q < 4; ++q) {                                               \
                float A = __builtin_amdgcn_exp2f(-acc[0][q]);                           \
                float B = __builtin_amdgcn_exp2f(-acc[1][q]);                           \
                float C = __builtin_amdgcn_exp2f(acc[2][q]);                            \
                float D = __builtin_amdgcn_exp2f(-acc[3][q]);                           \
                float ig = (C - 1.0f) * __builtin_amdgcn_rcpf((1.0f + A) * (C + 1.0f)); \
                float fc = cst[q] * __builtin_amdgcn_rcpf(1.0f + B);                    \
                float cv = fc + ig;                                                     \
                cst[q] = cv;                                                            \
                float E = __builtin_amdgcn_exp2f(TWO_L2E * cv);                         \
                float hv = (E - 1.0f) * __builtin_amdgcn_rcpf((1.0f + D) * (E + 1.0f)); \
                *(unsigned short*)(hwr + wbyte[q]) = f2bf(hv);                          \
            }                                                                           \
            __syncthreads();                                                            \
        }

        for (int t = 0; t < degv; t += 2) {
            LSTM_STEP(bufA, t)
            if (t + 1 < degv) {
                LSTM_STEP(bufB, t + 1)
            }
        }
#undef LSTM_STEP

        // write h_fin from hbuf[degv & 1]: 16 rows x 256B, 8B per thread
        const char* hf = (const char*)hbuf[degv & 1];
        int row = tid >> 5;
        int nd = nodes[row];
        if (nd >= 0) {
            int off = (tid & 31) * 8;
            int byte = (row * 256 + off) ^ ((row & 7) << 4);
            u16x4 v = *(const u16x4*)(hf + byte);
            *(u16x4*)(hfin + (size_t)nd * FF + off / 2) = v;
        }
    }
}

// ---------------- projection: one relation per block -> bf16 partial ---------
__global__ __launch_bounds__(256, 4) void k_projh(const unsigned short* __restrict__ fbf,
                                                  const unsigned short* __restrict__ hfin4,
                                                  const unsigned short* __restrict__ wstb,
                                                  const unsigned short* __restrict__ wntb,
                                                  const float* __restrict__ bo,
                                                  const int* __restrict__ D0, const int* __restrict__ D1,
                                                  const int* __restrict__ D2, const int* __restrict__ D3,
                                                  unsigned short* __restrict__ tmp) {
    int r = blockIdx.y;
    const int* dg = (r == 0) ? D0 : (r == 1) ? D1 : (r == 2) ? D2 : D3;
    int wv = threadIdx.x >> 6, l = threadIdx.x & 63;
    int n0 = blockIdx.x * 64 + wv * 16;
    int col = l & 15, grp = l >> 4;

    s16x8 af[4], ah[4];
    const unsigned short* fp = fbf + (size_t)(n0 + col) * FF + grp * 8;
    const unsigned short* hp = hfin4 + (size_t)r * NN * FF + (size_t)(n0 + col) * FF + grp * 8;
    int dval = dg[n0 + col];
    const s16x8 zfrag = {0, 0, 0, 0, 0, 0, 0, 0};
#pragma unroll
    for (int kt = 0; kt < 4; ++kt) {
        af[kt] = *(const s16x8*)(fp + kt * 32);
        s16x8 h = *(const s16x8*)(hp + kt * 32);
        ah[kt] = (dval > 0) ? h : zfrag;
    }

    f32x4 acc[8];
#pragma unroll
    for (int t = 0; t < 8; ++t) acc[t] = splat4(bo[r * OO + t * 16 + col]);

    const unsigned short* wsb = wstb + (size_t)r * OO * FF + col * FF + grp * 8;
    const unsigned short* wnb = wntb + (size_t)r * OO * FF + col * FF + grp * 8;
#pragma unroll
    for (int kt = 0; kt < 4; ++kt) {
#pragma unroll
        for (int t = 0; t < 8; ++t) {
            s16x8 b1 = *(const s16x8*)(wsb + t * 16 * FF + kt * 32);
            acc[t] = __builtin_amdgcn_mfma_f32_16x16x32_bf16(af[kt], b1, acc[t], 0, 0, 0);
            s16x8 b2 = *(const s16x8*)(wnb + t * 16 * FF + kt * 32);
            acc[t] = __builtin_amdgcn_mfma_f32_16x16x32_bf16(ah[kt], b2, acc[t], 0, 0, 0);
        }
    }
    unsigned short* tp = tmp + (size_t)r * NN * OO;
#pragma unroll
    for (int q = 0; q < 4; ++q) {
        int node = n0 + grp * 4 + q;
#pragma unroll
        for (int t = 0; t < 8; ++t)
            tp[node * OO + t * 16 + col] = f2bf(acc[t][q]);
    }
}

// ---------------- combine: out = mean[seg] + max(p0,p1) + max(p2,p3) ---------
__global__ void k_combine(const unsigned short* __restrict__ tmp,
                          const float* __restrict__ mean, const int* __restrict__ seg,
                          float* __restrict__ out) {
    int i = blockIdx.x * blockDim.x + threadIdx.x;
    int idx4 = i * 4;
    if (idx4 >= NN * OO) return;
    int node = idx4 >> 7;
    int dim = idx4 & 127;
    ushort4 p0 = *(const ushort4*)(tmp + idx4);
    ushort4 p1 = *(const ushort4*)(tmp + (size_t)NN * OO + idx4);
    ushort4 p2 = *(const ushort4*)(tmp + 2 * (size_t)NN * OO + idx4);
    ushort4 p3 = *(const ushort4*)(tmp + 3 * (size_t)NN * OO + idx4);
    float4 mv = *(const float4*)(mean + seg[node] * FF + dim);
    float4 o;
    o.x = mv.x + fmaxf(bf2f(p0.x), bf2f(p1.x)) + fmaxf(bf2f(p2.x), bf2f(p3.x));
    o.y = mv.y + fmaxf(bf2f(p0.y), bf2f(p1.y)) + fmaxf(bf2f(p2.y), bf2f(p3.y));
    o.z = mv.z + fmaxf(bf2f(p0.z), bf2f(p1.z)) + fmaxf(bf2f(p2.z), bf2f(p3.z));
    o.w = mv.w + fmaxf(bf2f(p0.w), bf2f(p1.w)) + fmaxf(bf2f(p2.w), bf2f(p3.w));
    *(float4*)(out + idx4) = o;
}

extern "C" void kernel_launch(void* const* d_in, const int* in_sizes, int n_in,
                              void* d_out, int out_size, void* d_ws, size_t ws_size,
                              hipStream_t stream) {
    const float* feat = (const float*)d_in[0];
    const int* nbr[4] = {(const int*)d_in[1], (const int*)d_in[3], (const int*)d_in[5], (const int*)d_in[7]};
    const int* dgp[4] = {(const int*)d_in[2], (const int*)d_in[4], (const int*)d_in[6], (const int*)d_in[8]};
    const int* seg   = (const int*)d_in[9];
    const float* Wih = (const float*)d_in[10];
    const float* Whh = (const float*)d_in[11];
    const float* lb  = (const float*)d_in[12];
    const float* Ws  = (const float*)d_in[13];
    const float* Wn  = (const float*)d_in[14];
    const float* bo  = (const float*)d_in[15];

    char* ws = (char*)d_ws;
    float*          mean  = (float*)(ws + 0);                      //     32,768
    unsigned short* fbf   = (unsigned short*)(ws + 32768);         // 10,240,000
    unsigned short* wihb  = (unsigned short*)(ws + 10272768);      //    524,288
    unsigned short* whhb  = (unsigned short*)(ws + 10797056);      //    524,288
    unsigned short* wstb  = (unsigned short*)(ws + 11321344);      //    131,072
    unsigned short* wntb  = (unsigned short*)(ws + 11452416);      //    131,072
    unsigned short* xih   = (unsigned short*)(ws + 11583488);      // 4x or 1x 40,960,000

    const int big = (ws_size >= 217039872ULL);
    size_t xih_bytes = big ? 163840000ULL : 40960000ULL;
    unsigned short* hfin4 = (unsigned short*)(ws + 11583488 + xih_bytes);          // 40,960,000
    int*            order4= (int*)(ws + 11583488 + xih_bytes + 40960000);          //    655,360
    int*            cnt4  = (int*)(ws + 11583488 + xih_bytes + 40960000 + 655360); //      1,024
    unsigned short* tmp   = xih;   // xih dead after lstm; 40,960,000 B for 4 bf16 partials

    hipMemsetAsync(order4, 0xFF, 655360, stream);
    hipMemsetAsync(cnt4, 0, 1024, stream);

    k_prep<<<1024, 256, 0, stream>>>(Wih, Whh, Ws, Wn, feat, wihb, whhb, wstb, wntb, fbf);
    k_segmean<<<64, 256, 0, stream>>>(feat, seg, mean);
    k_count<<<dim3(157, 4), 256, 0, stream>>>(dgp[0], dgp[1], dgp[2], dgp[3], cnt4);
    k_offsets<<<1, 64, 0, stream>>>(cnt4);
    k_scatter<<<dim3(157, 4), 256, 0, stream>>>(dgp[0], dgp[1], dgp[2], dgp[3], cnt4, order4);

    if (big) {
        k_xih<<<dim3(1250, 4), 256, 0, stream>>>(fbf, wihb, lb, xih, 0);
        k_lstm<<<dim3(LSTM_BLOCKS, 4), 512, 0, stream>>>(xih, whhb, order4,
                                                         nbr[0], nbr[1], nbr[2], nbr[3],
                                                         dgp[0], dgp[1], dgp[2], dgp[3], hfin4, 0);
    } else {
        for (int r = 0; r < 4; ++r) {
            k_xih<<<dim3(1250, 1), 256, 0, stream>>>(fbf, wihb, lb, xih, r);
            k_lstm<<<dim3(LSTM_BLOCKS, 1), 512, 0, stream>>>(xih, whhb, order4,
                                                             nbr[0], nbr[1], nbr[2], nbr[3],
                                                             dgp[0], dgp[1], dgp[2], dgp[3], hfin4, r);
        }
    }
    k_projh<<<dim3(625, 4), 256, 0, stream>>>(fbf, hfin4, wstb, wntb, bo,
                                              dgp[0], dgp[1], dgp[2], dgp[3], tmp);
    k_combine<<<5000, 256, 0, stream>>>(tmp, mean, seg, (float*)d_out);
}

// Round 11
// 533.330 us; speedup vs baseline: 1.1142x; 1.1142x over previous
//
#include <hip/hip_runtime.h>

#define NN 40000
#define DDEG 16
#define FF 128
#define OO 128
#define NG 512   // 4*F gates
#define XIH_ELEMS 20480000   // NN*NG u16 per relation
#define L2E 1.4426950408889634f
#define TWO_L2E 2.8853900817779268f

typedef short  s16x8 __attribute__((ext_vector_type(8)));
typedef unsigned short u16x8 __attribute__((ext_vector_type(8)));
typedef unsigned short u16x4 __attribute__((ext_vector_type(4)));
typedef float  f32x4 __attribute__((ext_vector_type(4)));

static_assert(sizeof(s16x8) == 16, "frag size");

__device__ __forceinline__ unsigned short f2bf(float f) {
    unsigned int u = __builtin_bit_cast(unsigned int, f);
    u += 0x7FFFu + ((u >> 16) & 1u);   // RNE
    return (unsigned short)(u >> 16);
}
__device__ __forceinline__ float bf2f(unsigned short s) {
    unsigned int u = ((unsigned int)s) << 16;
    return __builtin_bit_cast(float, u);
}
__device__ __forceinline__ f32x4 splat4(float v) { f32x4 r = {v, v, v, v}; return r; }

// ---- prep: weights -> bf16 with exp2 prescale; Ws/Wn transpose; feat cast ----
// gate-row scale: rows [0,256)+[384,512) (i,f,o): log2e; rows [256,384) (g): 2*log2e
__global__ void k_prep(const float* __restrict__ Wih, const float* __restrict__ Whh,
                       const float* __restrict__ Ws,  const float* __restrict__ Wn,
                       const float* __restrict__ feat,
                       unsigned short* __restrict__ wihb, unsigned short* __restrict__ whhb,
                       unsigned short* __restrict__ wstb, unsigned short* __restrict__ wntb,
                       unsigned short* __restrict__ fbf) {
    int i = blockIdx.x * blockDim.x + threadIdx.x;
    int stride = gridDim.x * blockDim.x;
    for (int idx = i; idx < 4 * NG * FF; idx += stride) {
        int row = (idx >> 7) & 511;
        float s = ((row >> 7) == 2) ? TWO_L2E : L2E;
        wihb[idx] = f2bf(Wih[idx] * s);
        whhb[idx] = f2bf(Whh[idx] * s);
    }
    for (int idx = i; idx < 4 * FF * OO; idx += stride) {
        int r = idx >> 14;
        int rem = idx & 16383;
        int o = rem >> 7;
        int k = rem & 127;
        wstb[idx] = f2bf(Ws[(r << 14) + (k << 7) + o]);
        wntb[idx] = f2bf(Wn[(r << 14) + (k << 7) + o]);
    }
    for (int idx4 = i * 4; idx4 < NN * FF; idx4 += stride * 4) {
        float4 v = *(const float4*)(feat + idx4);
        ushort4 o;
        o.x = f2bf(v.x); o.y = f2bf(v.y); o.z = f2bf(v.z); o.w = f2bf(v.w);
        *(ushort4*)(fbf + idx4) = o;
    }
}

// ---------------- segment mean (seg_ids sorted, G=64), float4 vectorized -----
__global__ void k_segmean(const float* __restrict__ feat, const int* __restrict__ seg,
                          float* __restrict__ mean) {
    int g = blockIdx.x;
    int lo, hi;
    { int a = 0, b = NN; while (a < b) { int m = (a + b) >> 1; if (seg[m] < g) a = m + 1; else b = m; } lo = a; }
    { int a = 0, b = NN; while (a < b) { int m = (a + b) >> 1; if (seg[m] < g + 1) a = m + 1; else b = m; } hi = a; }
    int tid = threadIdx.x;
    int d4 = tid & 31;
    int part = tid >> 5;
    float4 s = {0.f, 0.f, 0.f, 0.f};
    for (int row = lo + part; row < hi; row += 8) {
        float4 v = *(const float4*)(feat + (size_t)row * FF + d4 * 4);
        s.x += v.x; s.y += v.y; s.z += v.z; s.w += v.w;
    }
    __shared__ float ps[8][128];
    ps[part][d4 * 4 + 0] = s.x; ps[part][d4 * 4 + 1] = s.y;
    ps[part][d4 * 4 + 2] = s.z; ps[part][d4 * 4 + 3] = s.w;
    __syncthreads();
    if (tid < 128) {
        float tot = 0.f;
#pragma unroll
        for (int p = 0; p < 8; ++p) tot += ps[p][tid];
        mean[g * FF + tid] = tot / fmaxf((float)(hi - lo), 1.0f);
    }
}

// ---------------- deg bucketing, all 4 relations (two-level histogram) -------
__global__ void k_count(const int* __restrict__ D0, const int* __restrict__ D1,
                        const int* __restrict__ D2, const int* __restrict__ D3,
                        int* __restrict__ cnt4) {
    int r = blockIdx.y;
    const int* dg = (r == 0) ? D0 : (r == 1) ? D1 : (r == 2) ? D2 : D3;
    __shared__ int lcnt[17];
    if (threadIdx.x < 17) lcnt[threadIdx.x] = 0;
    __syncthreads();
    int n = blockIdx.x * blockDim.x + threadIdx.x;
    if (n < NN) { int d = dg[n]; if (d > 0) atomicAdd(&lcnt[d], 1); }
    __syncthreads();
    if (threadIdx.x >= 1 && threadIdx.x < 17 && lcnt[threadIdx.x])
        atomicAdd(&cnt4[r * 64 + threadIdx.x], lcnt[threadIdx.x]);
}
__global__ void k_offsets(int* __restrict__ cnt4) {
    int r = threadIdx.x;
    if (r < 4 && blockIdx.x == 0) {
        int running = 0;
        for (int d = 16; d >= 1; --d) {
            cnt4[r * 64 + 40 + d] = running;
            running += (cnt4[r * 64 + d] + 15) & ~15;
        }
    }
}
__global__ void k_scatter(const int* __restrict__ D0, const int* __restrict__ D1,
                          const int* __restrict__ D2, const int* __restrict__ D3,
                          int* __restrict__ cnt4, int* __restrict__ order4) {
    int r = blockIdx.y;
    const int* dg = (r == 0) ? D0 : (r == 1) ? D1 : (r == 2) ? D2 : D3;
    __shared__ int lcnt[17];
    __shared__ int gbase[17];
    if (threadIdx.x < 17) lcnt[threadIdx.x] = 0;
    __syncthreads();
    int n = blockIdx.x * blockDim.x + threadIdx.x;
    int d = 0, rank = 0;
    if (n < NN) { d = dg[n]; if (d > 0) rank = atomicAdd(&lcnt[d], 1); }
    __syncthreads();
    if (threadIdx.x >= 1 && threadIdx.x < 17 && lcnt[threadIdx.x])
        gbase[threadIdx.x] = atomicAdd(&cnt4[r * 64 + 40 + threadIdx.x], lcnt[threadIdx.x]);
    __syncthreads();
    if (n < NN && d > 0) order4[r * 40960 + gbase[d] + rank] = n;
}

// ---------------- Xih = feat @ Wih[r].T + b(scaled), 8-wave-permuted layout --
// u16 index in 512-row: (T&7)*64 + col*4 + (T>>3) for gate-tile T.
// 32 nodes/block (2 A-sets amortize each B-frag); 4 waves, tiles {w+4j}.
__global__ __launch_bounds__(256, 4) void k_xih(const unsigned short* __restrict__ fbf,
                                                const unsigned short* __restrict__ wihb,
                                                const float* __restrict__ lb,
                                                unsigned short* __restrict__ xih, int rbase) {
    int r = rbase + blockIdx.y;
    unsigned short* xr = xih + (size_t)blockIdx.y * XIH_ELEMS;
    int tid = threadIdx.x;
    int w = tid >> 6;
    int l = tid & 63;
    int n0 = blockIdx.x * 32;
    int col = l & 15, grp = l >> 4;

    f32x4 acc[8][2];
#pragma unroll
    for (int j = 0; j < 8; ++j) {
        float sc = (((w + 4 * j) >> 3) == 2) ? TWO_L2E : L2E;
        f32x4 b = splat4(lb[r * NG + (w + 4 * j) * 16 + col] * sc);
        acc[j][0] = b; acc[j][1] = b;
    }

    s16x8 a0[4], a1[4];
    const unsigned short* ap0 = fbf + (size_t)(n0 + col) * FF + grp * 8;
    const unsigned short* ap1 = fbf + (size_t)(n0 + 16 + col) * FF + grp * 8;
#pragma unroll
    for (int kt = 0; kt < 4; ++kt) {
        a0[kt] = *(const s16x8*)(ap0 + kt * 32);
        a1[kt] = *(const s16x8*)(ap1 + kt * 32);
    }

    const unsigned short* wb = wihb + (size_t)r * NG * FF + col * FF + grp * 8;
#pragma unroll
    for (int j = 0; j < 8; ++j) {
#pragma unroll
        for (int kt = 0; kt < 4; ++kt) {
            s16x8 b = *(const s16x8*)(wb + (size_t)(w + 4 * j) * 16 * FF + kt * 32);
            acc[j][0] = __builtin_amdgcn_mfma_f32_16x16x32_bf16(a0[kt], b, acc[j][0], 0, 0, 0);
            acc[j][1] = __builtin_amdgcn_mfma_f32_16x16x32_bf16(a1[kt], b, acc[j][1], 0, 0, 0);
        }
    }
    // store: tile T=w+4j -> u16 idx (T&7)*64+col*4+(T>>3); j even -> slot w, j odd -> slot w+4
#pragma unroll
    for (int s = 0; s < 2; ++s) {
#pragma unroll
        for (int q = 0; q < 4; ++q) {
            int node = n0 + s * 16 + grp * 4 + q;
            u16x4 ue, uo;
#pragma unroll
            for (int m = 0; m < 4; ++m) {
                ue[m] = f2bf(acc[2 * m][s][q]);
                uo[m] = f2bf(acc[2 * m + 1][s][q]);
            }
            *(u16x4*)(xr + (size_t)node * NG + w * 64 + col * 4) = ue;
            *(u16x4*)(xr + (size_t)node * NG + (w + 4) * 64 + col * 4) = uo;
        }
    }
}

// ---------------- bucketed LSTM: 8 waves x 4 tiles, Whh in regs --------------
// 512 thr; wave w owns tiles {w+8j}; i/f/g/o quadruple thread-local; single-
// step register prefetch (r9 structure); transposed nbr-offset table (one
// ds_read_b128/step); f32x4-vectorized activation arithmetic (v_pk_*).
#define LSTM_BLOCKS 1280
#define LSTM_GROUPS 2
__global__ __launch_bounds__(512, 4) void k_lstm(const unsigned short* __restrict__ xih,
                                                 const unsigned short* __restrict__ whhb,
                                                 const int* __restrict__ order4,
                                                 const int* __restrict__ N0, const int* __restrict__ N1,
                                                 const int* __restrict__ N2, const int* __restrict__ N3,
                                                 const int* __restrict__ D0, const int* __restrict__ D1,
                                                 const int* __restrict__ D2, const int* __restrict__ D3,
                                                 unsigned short* __restrict__ hfin4, int rbase) {
    int r = rbase + blockIdx.y;
    const unsigned short* xr = xih + (size_t)blockIdx.y * XIH_ELEMS;
    const int* nbr = (r == 0) ? N0 : (r == 1) ? N1 : (r == 2) ? N2 : N3;
    const int* deg = (r == 0) ? D0 : (r == 1) ? D1 : (r == 2) ? D2 : D3;
    const int* order = order4 + r * 40960;
    unsigned short* hfin = hfin4 + (size_t)r * NN * FF;

    __shared__ int nodes[16];
    __shared__ int nbrs_t[16][16];             // [t][node]: premultiplied byte offsets
    __shared__ unsigned short hbuf[2][2048];   // 2 x (16 rows x 128 dims bf16), XOR-swizzled
    int tid = threadIdx.x;
    int w = tid >> 6, l = tid & 63;
    int col = l & 15, grp = l >> 4;

    // Whh slice: tiles {w+8j}, 16 frags = 64 regs
    const unsigned short* whhp = whhb + (size_t)r * NG * FF + col * FF + grp * 8;
    s16x8 breg[4][4];
#pragma unroll
    for (int j = 0; j < 4; ++j)
#pragma unroll
        for (int kt = 0; kt < 4; ++kt)
            breg[j][kt] = *(const s16x8*)(whhp + (size_t)(w + 8 * j) * 16 * FF + kt * 32);

    const char* xbc = (const char*)(xr + w * 64 + col * 4);

    int rbyte[4];
#pragma unroll
    for (int kt = 0; kt < 4; ++kt)
        rbyte[kt] = (col * 256 + kt * 64 + grp * 16) ^ ((col & 7) << 4);
    int wbyte[4];
#pragma unroll
    for (int q = 0; q < 4; ++q) {
        int node = grp * 4 + q;
        wbyte[q] = (node * 256 + (w * 16 + col) * 2) ^ ((node & 7) << 4);
    }

    for (int gi = 0; gi < LSTM_GROUPS; ++gi) {
        int g0 = (blockIdx.x + gi * LSTM_BLOCKS) * 16;
        __syncthreads();
        if (tid < 16) nodes[tid] = order[g0 + tid];
        __syncthreads();
        if (nodes[0] < 0) continue;          // uniform
        int degv = deg[nodes[0]];

        if (tid < 256) {
            int row = tid >> 4, t = tid & 15;   // global read stays node-coalesced
            int nd = nodes[row]; if (nd < 0) nd = 0;
            nbrs_t[t][row] = nbr[nd * DDEG + t] << 10;
        }
        __syncthreads();

        f32x4 cst = splat4(0.f);

        // single-step register prefetch (r9 structure)
        u16x4 cur[4], nxt[4];
        {
            int4 of0 = *(const int4*)&nbrs_t[0][grp * 4];
            cur[0] = *(const u16x4*)(xbc + (unsigned)of0.x);
            cur[1] = *(const u16x4*)(xbc + (unsigned)of0.y);
            cur[2] = *(const u16x4*)(xbc + (unsigned)of0.z);
            cur[3] = *(const u16x4*)(xbc + (unsigned)of0.w);
        }

        for (int t = 0; t < degv; ++t) {
            if (t + 1 < degv) {
                int4 ofn = *(const int4*)&nbrs_t[t + 1][grp * 4];
                nxt[0] = *(const u16x4*)(xbc + (unsigned)ofn.x);
                nxt[1] = *(const u16x4*)(xbc + (unsigned)ofn.y);
                nxt[2] = *(const u16x4*)(xbc + (unsigned)ofn.z);
                nxt[3] = *(const u16x4*)(xbc + (unsigned)ofn.w);
            }
            f32x4 acc[4];
#pragma unroll
            for (int j = 0; j < 4; ++j)
#pragma unroll
                for (int q = 0; q < 4; ++q)
                    acc[j][q] = bf2f(cur[q][j]);

            if (t > 0) {
                const char* hrd = (const char*)hbuf[t & 1];
#pragma unroll
                for (int kt = 0; kt < 4; ++kt) {
                    s16x8 ah = *(const s16x8*)(hrd + rbyte[kt]);
#pragma unroll
                    for (int j = 0; j < 4; ++j)
                        acc[j] = __builtin_amdgcn_mfma_f32_16x16x32_bf16(ah, breg[j][kt], acc[j], 0, 0, 0);
                }
            }
            // exp2-domain shared-rcp activations, f32x4-vectorized arithmetic:
            // A=2^-i', B=2^-f', C=2^g', D=2^-o'; ig=(C-1)/((1+A)(C+1));
            // fc=c/(1+B); cv=fc+ig; h=(E-1)/((1+D)(E+1)), E=2^(2log2e*cv)
            char* hwr = (char*)hbuf[(t + 1) & 1];
            {
                f32x4 Av, Bv, Cv, Dv;
#pragma unroll
                for (int q = 0; q < 4; ++q) {
                    Av[q] = __builtin_amdgcn_exp2f(-acc[0][q]);
                    Bv[q] = __builtin_amdgcn_exp2f(-acc[1][q]);
                    Cv[q] = __builtin_amdgcn_exp2f(acc[2][q]);
                    Dv[q] = __builtin_amdgcn_exp2f(-acc[3][q]);
                }
                f32x4 d1 = (Av + 1.0f) * (Cv + 1.0f);
                f32x4 d2 = Bv + 1.0f;
                f32x4 r1, r2;
#pragma unroll
                for (int q = 0; q < 4; ++q) {
                    r1[q] = __builtin_amdgcn_rcpf(d1[q]);
                    r2[q] = __builtin_amdgcn_rcpf(d2[q]);
                }
                f32x4 cv = cst * r2 + (Cv - 1.0f) * r1;
                cst = cv;
                f32x4 ecv = cv * TWO_L2E;
                f32x4 Ev;
#pragma unroll
                for (int q = 0; q < 4; ++q) Ev[q] = __builtin_amdgcn_exp2f(ecv[q]);
                f32x4 d3 = (Dv + 1.0f) * (Ev + 1.0f);
                f32x4 r3;
#pragma unroll
                for (int q = 0; q < 4; ++q) r3[q] = __builtin_amdgcn_rcpf(d3[q]);
                f32x4 hvv = (Ev - 1.0f) * r3;
#pragma unroll
                for (int q = 0; q < 4; ++q)
                    *(unsigned short*)(hwr + wbyte[q]) = f2bf(hvv[q]);
            }
#pragma unroll
            for (int q = 0; q < 4; ++q) cur[q] = nxt[q];
            __syncthreads();
        }
        // write h_fin from hbuf[degv & 1]: 16 rows x 256B, 8B per thread
        const char* hf = (const char*)hbuf[degv & 1];
        int row = tid >> 5;
        int nd = nodes[row];
        if (nd >= 0) {
            int off = (tid & 31) * 8;
            int byte = (row * 256 + off) ^ ((row & 7) << 4);
            u16x4 v = *(const u16x4*)(hf + byte);
            *(u16x4*)(hfin + (size_t)nd * FF + off / 2) = v;
        }
    }
}

// ---------------- projection: one relation per block -> bf16 partial ---------
__global__ __launch_bounds__(256, 4) void k_projh(const unsigned short* __restrict__ fbf,
                                                  const unsigned short* __restrict__ hfin4,
                                                  const unsigned short* __restrict__ wstb,
                                                  const unsigned short* __restrict__ wntb,
                                                  const float* __restrict__ bo,
                                                  const int* __restrict__ D0, const int* __restrict__ D1,
                                                  const int* __restrict__ D2, const int* __restrict__ D3,
                                                  unsigned short* __restrict__ tmp) {
    int r = blockIdx.y;
    const int* dg = (r == 0) ? D0 : (r == 1) ? D1 : (r == 2) ? D2 : D3;
    int wv = threadIdx.x >> 6, l = threadIdx.x & 63;
    int n0 = blockIdx.x * 64 + wv * 16;
    int col = l & 15, grp = l >> 4;

    s16x8 af[4], ah[4];
    const unsigned short* fp = fbf + (size_t)(n0 + col) * FF + grp * 8;
    const unsigned short* hp = hfin4 + (size_t)r * NN * FF + (size_t)(n0 + col) * FF + grp * 8;
    int dval = dg[n0 + col];
    const s16x8 zfrag = {0, 0, 0, 0, 0, 0, 0, 0};
#pragma unroll
    for (int kt = 0; kt < 4; ++kt) {
        af[kt] = *(const s16x8*)(fp + kt * 32);
        s16x8 h = *(const s16x8*)(hp + kt * 32);
        ah[kt] = (dval > 0) ? h : zfrag;
    }

    f32x4 acc[8];
#pragma unroll
    for (int t = 0; t < 8; ++t) acc[t] = splat4(bo[r * OO + t * 16 + col]);

    const unsigned short* wsb = wstb + (size_t)r * OO * FF + col * FF + grp * 8;
    const unsigned short* wnb = wntb + (size_t)r * OO * FF + col * FF + grp * 8;
#pragma unroll
    for (int kt = 0; kt < 4; ++kt) {
#pragma unroll
        for (int t = 0; t < 8; ++t) {
            s16x8 b1 = *(const s16x8*)(wsb + t * 16 * FF + kt * 32);
            acc[t] = __builtin_amdgcn_mfma_f32_16x16x32_bf16(af[kt], b1, acc[t], 0, 0, 0);
            s16x8 b2 = *(const s16x8*)(wnb + t * 16 * FF + kt * 32);
            acc[t] = __builtin_amdgcn_mfma_f32_16x16x32_bf16(ah[kt], b2, acc[t], 0, 0, 0);
        }
    }
    unsigned short* tp = tmp + (size_t)r * NN * OO;
#pragma unroll
    for (int q = 0; q < 4; ++q) {
        int node = n0 + grp * 4 + q;
#pragma unroll
        for (int t = 0; t < 8; ++t)
            tp[node * OO + t * 16 + col] = f2bf(acc[t][q]);
    }
}

// ---------------- combine: out = mean[seg] + max(p0,p1) + max(p2,p3) ---------
__global__ void k_combine(const unsigned short* __restrict__ tmp,
                          const float* __restrict__ mean, const int* __restrict__ seg,
                          float* __restrict__ out) {
    int i = blockIdx.x * blockDim.x + threadIdx.x;
    int idx4 = i * 4;
    if (idx4 >= NN * OO) return;
    int node = idx4 >> 7;
    int dim = idx4 & 127;
    ushort4 p0 = *(const ushort4*)(tmp + idx4);
    ushort4 p1 = *(const ushort4*)(tmp + (size_t)NN * OO + idx4);
    ushort4 p2 = *(const ushort4*)(tmp + 2 * (size_t)NN * OO + idx4);
    ushort4 p3 = *(const ushort4*)(tmp + 3 * (size_t)NN * OO + idx4);
    float4 mv = *(const float4*)(mean + seg[node] * FF + dim);
    float4 o;
    o.x = mv.x + fmaxf(bf2f(p0.x), bf2f(p1.x)) + fmaxf(bf2f(p2.x), bf2f(p3.x));
    o.y = mv.y + fmaxf(bf2f(p0.y), bf2f(p1.y)) + fmaxf(bf2f(p2.y), bf2f(p3.y));
    o.z = mv.z + fmaxf(bf2f(p0.z), bf2f(p1.z)) + fmaxf(bf2f(p2.z), bf2f(p3.z));
    o.w = mv.w + fmaxf(bf2f(p0.w), bf2f(p1.w)) + fmaxf(bf2f(p2.w), bf2f(p3.w));
    *(float4*)(out + idx4) = o;
}

extern "C" void kernel_launch(void* const* d_in, const int* in_sizes, int n_in,
                              void* d_out, int out_size, void* d_ws, size_t ws_size,
                              hipStream_t stream) {
    const float* feat = (const float*)d_in[0];
    const int* nbr[4] = {(const int*)d_in[1], (const int*)d_in[3], (const int*)d_in[5], (const int*)d_in[7]};
    const int* dgp[4] = {(const int*)d_in[2], (const int*)d_in[4], (const int*)d_in[6], (const int*)d_in[8]};
    const int* seg   = (const int*)d_in[9];
    const float* Wih = (const float*)d_in[10];
    const float* Whh = (const float*)d_in[11];
    const float* lb  = (const float*)d_in[12];
    const float* Ws  = (const float*)d_in[13];
    const float* Wn  = (const float*)d_in[14];
    const float* bo  = (const float*)d_in[15];

    char* ws = (char*)d_ws;
    float*          mean  = (float*)(ws + 0);                      //     32,768
    unsigned short* fbf   = (unsigned short*)(ws + 32768);         // 10,240,000
    unsigned short* wihb  = (unsigned short*)(ws + 10272768);      //    524,288
    unsigned short* whhb  = (unsigned short*)(ws + 10797056);      //    524,288
    unsigned short* wstb  = (unsigned short*)(ws + 11321344);      //    131,072
    unsigned short* wntb  = (unsigned short*)(ws + 11452416);      //    131,072
    unsigned short* xih   = (unsigned short*)(ws + 11583488);      // 4x or 1x 40,960,000

    const int big = (ws_size >= 217039872ULL);
    size_t xih_bytes = big ? 163840000ULL : 40960000ULL;
    unsigned short* hfin4 = (unsigned short*)(ws + 11583488 + xih_bytes);          // 40,960,000
    int*            order4= (int*)(ws + 11583488 + xih_bytes + 40960000);          //    655,360
    int*            cnt4  = (int*)(ws + 11583488 + xih_bytes + 40960000 + 655360); //      1,024
    unsigned short* tmp   = xih;   // xih dead after lstm; 40,960,000 B for 4 bf16 partials

    hipMemsetAsync(order4, 0xFF, 655360, stream);
    hipMemsetAsync(cnt4, 0, 1024, stream);

    k_prep<<<1024, 256, 0, stream>>>(Wih, Whh, Ws, Wn, feat, wihb, whhb, wstb, wntb, fbf);
    k_segmean<<<64, 256, 0, stream>>>(feat, seg, mean);
    k_count<<<dim3(157, 4), 256, 0, stream>>>(dgp[0], dgp[1], dgp[2], dgp[3], cnt4);
    k_offsets<<<1, 64, 0, stream>>>(cnt4);
    k_scatter<<<dim3(157, 4), 256, 0, stream>>>(dgp[0], dgp[1], dgp[2], dgp[3], cnt4, order4);

    if (big) {
        k_xih<<<dim3(1250, 4), 256, 0, stream>>>(fbf, wihb, lb, xih, 0);
        k_lstm<<<dim3(LSTM_BLOCKS, 4), 512, 0, stream>>>(xih, whhb, order4,
                                                         nbr[0], nbr[1], nbr[2], nbr[3],
                                                         dgp[0], dgp[1], dgp[2], dgp[3], hfin4, 0);
    } else {
        for (int r = 0; r < 4; ++r) {
            k_xih<<<dim3(1250, 1), 256, 0, stream>>>(fbf, wihb, lb, xih, r);
            k_lstm<<<dim3(LSTM_BLOCKS, 1), 512, 0, stream>>>(xih, whhb, order4,
                                                             nbr[0], nbr[1], nbr[2], nbr[3],
                                                             dgp[0], dgp[1], dgp[2], dgp[3], hfin4, r);
        }
    }
    k_projh<<<dim3(625, 4), 256, 0, stream>>>(fbf, hfin4, wstb, wntb, bo,
                                              dgp[0], dgp[1], dgp[2], dgp[3], tmp);
    k_combine<<<5000, 256, 0, stream>>>(tmp, mean, seg, (float*)d_out);
}

// Round 12
// 514.937 us; speedup vs baseline: 1.1540x; 1.0357x over previous
//
#include <hip/hip_runtime.h>
#include <hip/hip_bf16.h>

#define NN 40000
#define DDEG 16
#define FF 128
#define OO 128
#define NG 512   // 4*F gates
#define XIH_ELEMS 20480000   // NN*NG u16 per relation
#define L2E 1.4426950408889634f
#define TWO_L2E 2.8853900817779268f

typedef short  s16x8 __attribute__((ext_vector_type(8)));
typedef unsigned short u16x8 __attribute__((ext_vector_type(8)));
typedef unsigned short u16x4 __attribute__((ext_vector_type(4)));
typedef float  f32x4 __attribute__((ext_vector_type(4)));

static_assert(sizeof(s16x8) == 16, "frag size");
static_assert(sizeof(__hip_bfloat16) == 2, "bf16 size");

__device__ __forceinline__ unsigned short f2bf(float f) {
    __hip_bfloat16 h = __float2bfloat16(f);   // RNE; compiler emits v_cvt_pk_bf16_f32
    return __builtin_bit_cast(unsigned short, h);
}
__device__ __forceinline__ float bf2f(unsigned short s) {
    unsigned int u = ((unsigned int)s) << 16;
    return __builtin_bit_cast(float, u);
}
__device__ __forceinline__ f32x4 splat4(float v) { f32x4 r = {v, v, v, v}; return r; }

// ---- prep: weights -> bf16 with exp2 prescale; Ws/Wn transpose; feat cast ----
// gate-row scale: rows [0,256)+[384,512) (i,f,o): log2e; rows [256,384) (g): 2*log2e
__global__ void k_prep(const float* __restrict__ Wih, const float* __restrict__ Whh,
                       const float* __restrict__ Ws,  const float* __restrict__ Wn,
                       const float* __restrict__ feat,
                       unsigned short* __restrict__ wihb, unsigned short* __restrict__ whhb,
                       unsigned short* __restrict__ wstb, unsigned short* __restrict__ wntb,
                       unsigned short* __restrict__ fbf) {
    int i = blockIdx.x * blockDim.x + threadIdx.x;
    int stride = gridDim.x * blockDim.x;
    for (int idx = i; idx < 4 * NG * FF; idx += stride) {
        int row = (idx >> 7) & 511;
        float s = ((row >> 7) == 2) ? TWO_L2E : L2E;
        wihb[idx] = f2bf(Wih[idx] * s);
        whhb[idx] = f2bf(Whh[idx] * s);
    }
    for (int idx = i; idx < 4 * FF * OO; idx += stride) {
        int r = idx >> 14;
        int rem = idx & 16383;
        int o = rem >> 7;
        int k = rem & 127;
        wstb[idx] = f2bf(Ws[(r << 14) + (k << 7) + o]);
        wntb[idx] = f2bf(Wn[(r << 14) + (k << 7) + o]);
    }
    for (int idx4 = i * 4; idx4 < NN * FF; idx4 += stride * 4) {
        float4 v = *(const float4*)(feat + idx4);
        ushort4 o;
        o.x = f2bf(v.x); o.y = f2bf(v.y); o.z = f2bf(v.z); o.w = f2bf(v.w);
        *(ushort4*)(fbf + idx4) = o;
    }
}

// ---------------- segment mean (seg_ids sorted, G=64), 512 thr ---------------
__global__ void k_segmean(const float* __restrict__ feat, const int* __restrict__ seg,
                          float* __restrict__ mean) {
    int g = blockIdx.x;
    int lo, hi;
    { int a = 0, b = NN; while (a < b) { int m = (a + b) >> 1; if (seg[m] < g) a = m + 1; else b = m; } lo = a; }
    { int a = 0, b = NN; while (a < b) { int m = (a + b) >> 1; if (seg[m] < g + 1) a = m + 1; else b = m; } hi = a; }
    int tid = threadIdx.x;
    int d4 = tid & 31;          // float4 slot
    int part = tid >> 5;        // 16 row-partitions
    float4 s = {0.f, 0.f, 0.f, 0.f};
    for (int row = lo + part; row < hi; row += 16) {
        float4 v = *(const float4*)(feat + (size_t)row * FF + d4 * 4);
        s.x += v.x; s.y += v.y; s.z += v.z; s.w += v.w;
    }
    __shared__ float ps[16][128];
    ps[part][d4 * 4 + 0] = s.x; ps[part][d4 * 4 + 1] = s.y;
    ps[part][d4 * 4 + 2] = s.z; ps[part][d4 * 4 + 3] = s.w;
    __syncthreads();
    if (tid < 128) {
        float tot = 0.f;
#pragma unroll
        for (int p = 0; p < 16; ++p) tot += ps[p][tid];
        mean[g * FF + tid] = tot / fmaxf((float)(hi - lo), 1.0f);
    }
}

// ---------------- deg bucketing, all 4 relations (two-level histogram) -------
__global__ void k_count(const int* __restrict__ D0, const int* __restrict__ D1,
                        const int* __restrict__ D2, const int* __restrict__ D3,
                        int* __restrict__ cnt4) {
    int r = blockIdx.y;
    const int* dg = (r == 0) ? D0 : (r == 1) ? D1 : (r == 2) ? D2 : D3;
    __shared__ int lcnt[17];
    if (threadIdx.x < 17) lcnt[threadIdx.x] = 0;
    __syncthreads();
    int n = blockIdx.x * blockDim.x + threadIdx.x;
    if (n < NN) { int d = dg[n]; if (d > 0) atomicAdd(&lcnt[d], 1); }
    __syncthreads();
    if (threadIdx.x >= 1 && threadIdx.x < 17 && lcnt[threadIdx.x])
        atomicAdd(&cnt4[r * 64 + threadIdx.x], lcnt[threadIdx.x]);
}
__global__ void k_offsets(int* __restrict__ cnt4) {
    int r = threadIdx.x;
    if (r < 4 && blockIdx.x == 0) {
        int running = 0;
        for (int d = 16; d >= 1; --d) {
            cnt4[r * 64 + 40 + d] = running;
            running += (cnt4[r * 64 + d] + 15) & ~15;
        }
    }
}
__global__ void k_scatter(const int* __restrict__ D0, const int* __restrict__ D1,
                          const int* __restrict__ D2, const int* __restrict__ D3,
                          int* __restrict__ cnt4, int* __restrict__ order4) {
    int r = blockIdx.y;
    const int* dg = (r == 0) ? D0 : (r == 1) ? D1 : (r == 2) ? D2 : D3;
    __shared__ int lcnt[17];
    __shared__ int gbase[17];
    if (threadIdx.x < 17) lcnt[threadIdx.x] = 0;
    __syncthreads();
    int n = blockIdx.x * blockDim.x + threadIdx.x;
    int d = 0, rank = 0;
    if (n < NN) { d = dg[n]; if (d > 0) rank = atomicAdd(&lcnt[d], 1); }
    __syncthreads();
    if (threadIdx.x >= 1 && threadIdx.x < 17 && lcnt[threadIdx.x])
        gbase[threadIdx.x] = atomicAdd(&cnt4[r * 64 + 40 + threadIdx.x], lcnt[threadIdx.x]);
    __syncthreads();
    if (n < NN && d > 0) order4[r * 40960 + gbase[d] + rank] = n;
}

// ---------------- Xih = feat @ Wih[r].T + b(scaled), 8-wave-permuted layout --
// u16 index in 512-row: (T&7)*64 + col*4 + (T>>3) for gate-tile T.
__global__ __launch_bounds__(256, 4) void k_xih(const unsigned short* __restrict__ fbf,
                                                const unsigned short* __restrict__ wihb,
                                                const float* __restrict__ lb,
                                                unsigned short* __restrict__ xih, int rbase) {
    int r = rbase + blockIdx.y;
    unsigned short* xr = xih + (size_t)blockIdx.y * XIH_ELEMS;
    int tid = threadIdx.x;
    int w = tid >> 6;
    int l = tid & 63;
    int n0 = blockIdx.x * 32;
    int col = l & 15, grp = l >> 4;

    f32x4 acc[8][2];
#pragma unroll
    for (int j = 0; j < 8; ++j) {
        float sc = (((w + 4 * j) >> 3) == 2) ? TWO_L2E : L2E;
        f32x4 b = splat4(lb[r * NG + (w + 4 * j) * 16 + col] * sc);
        acc[j][0] = b; acc[j][1] = b;
    }

    s16x8 a0[4], a1[4];
    const unsigned short* ap0 = fbf + (size_t)(n0 + col) * FF + grp * 8;
    const unsigned short* ap1 = fbf + (size_t)(n0 + 16 + col) * FF + grp * 8;
#pragma unroll
    for (int kt = 0; kt < 4; ++kt) {
        a0[kt] = *(const s16x8*)(ap0 + kt * 32);
        a1[kt] = *(const s16x8*)(ap1 + kt * 32);
    }

    const unsigned short* wb = wihb + (size_t)r * NG * FF + col * FF + grp * 8;
#pragma unroll
    for (int j = 0; j < 8; ++j) {
#pragma unroll
        for (int kt = 0; kt < 4; ++kt) {
            s16x8 b = *(const s16x8*)(wb + (size_t)(w + 4 * j) * 16 * FF + kt * 32);
            acc[j][0] = __builtin_amdgcn_mfma_f32_16x16x32_bf16(a0[kt], b, acc[j][0], 0, 0, 0);
            acc[j][1] = __builtin_amdgcn_mfma_f32_16x16x32_bf16(a1[kt], b, acc[j][1], 0, 0, 0);
        }
    }
#pragma unroll
    for (int s = 0; s < 2; ++s) {
#pragma unroll
        for (int q = 0; q < 4; ++q) {
            int node = n0 + s * 16 + grp * 4 + q;
            u16x4 ue, uo;
#pragma unroll
            for (int m = 0; m < 4; ++m) {
                ue[m] = f2bf(acc[2 * m][s][q]);
                uo[m] = f2bf(acc[2 * m + 1][s][q]);
            }
            *(u16x4*)(xr + (size_t)node * NG + w * 64 + col * 4) = ue;
            *(u16x4*)(xr + (size_t)node * NG + (w + 4) * 64 + col * 4) = uo;
        }
    }
}

// ---------------- bucketed LSTM: 8 waves x 4 tiles, Whh in regs --------------
// 512 thr; one 16-node group per block (grid 2560 x 4); wave w owns tiles
// {w+8j}; i/f/g/o quadruple thread-local; single-step register prefetch with
// sentinel row (branchless); exp2-domain shared-rcp activations.
#define LSTM_BLOCKS 2560
__global__ __launch_bounds__(512, 4) void k_lstm(const unsigned short* __restrict__ xih,
                                                 const unsigned short* __restrict__ whhb,
                                                 const int* __restrict__ order4,
                                                 const int* __restrict__ N0, const int* __restrict__ N1,
                                                 const int* __restrict__ N2, const int* __restrict__ N3,
                                                 const int* __restrict__ D0, const int* __restrict__ D1,
                                                 const int* __restrict__ D2, const int* __restrict__ D3,
                                                 unsigned short* __restrict__ hfin4, int rbase) {
    int r = rbase + blockIdx.y;
    const unsigned short* xr = xih + (size_t)blockIdx.y * XIH_ELEMS;
    const int* nbr = (r == 0) ? N0 : (r == 1) ? N1 : (r == 2) ? N2 : N3;
    const int* deg = (r == 0) ? D0 : (r == 1) ? D1 : (r == 2) ? D2 : D3;
    const int* order = order4 + r * 40960;
    unsigned short* hfin = hfin4 + (size_t)r * NN * FF;

    __shared__ int nodes[16];
    __shared__ int nbrs_t[17][16];             // [t][node], sentinel row 16
    __shared__ unsigned short hbuf[2][2048];   // 2 x (16 rows x 128 dims bf16), XOR-swizzled
    int tid = threadIdx.x;
    int w = tid >> 6, l = tid & 63;
    int col = l & 15, grp = l >> 4;

    int g0 = blockIdx.x * 16;
    if (tid < 16) nodes[tid] = order[g0 + tid];
    __syncthreads();
    if (nodes[0] < 0) return;          // uniform
    int degv = deg[nodes[0]];

    // Whh slice: tiles {w+8j}, 16 frags = 64 regs
    const unsigned short* whhp = whhb + (size_t)r * NG * FF + col * FF + grp * 8;
    s16x8 breg[4][4];
#pragma unroll
    for (int j = 0; j < 4; ++j)
#pragma unroll
        for (int kt = 0; kt < 4; ++kt)
            breg[j][kt] = *(const s16x8*)(whhp + (size_t)(w + 8 * j) * 16 * FF + kt * 32);

    const char* xbc = (const char*)(xr + w * 64 + col * 4);

    int rbyte[4];
#pragma unroll
    for (int kt = 0; kt < 4; ++kt)
        rbyte[kt] = (col * 256 + kt * 64 + grp * 16) ^ ((col & 7) << 4);
    int wbyte[4];
#pragma unroll
    for (int q = 0; q < 4; ++q) {
        int node = grp * 4 + q;
        wbyte[q] = (node * 256 + (w * 16 + col) * 2) ^ ((node & 7) << 4);
    }

    if (tid < 256) {
        int row = tid >> 4, t = tid & 15;   // global read node-coalesced
        int nd = nodes[row]; if (nd < 0) nd = 0;
        nbrs_t[t][row] = nbr[nd * DDEG + t] << 10;
    }
    if (tid < 16) nbrs_t[16][tid] = 0;     // sentinel (branchless prefetch)
    __syncthreads();

    f32x4 cst = splat4(0.f);

    u16x4 cur[4], nxt[4];
    {
        int4 of0 = *(const int4*)&nbrs_t[0][grp * 4];
        cur[0] = *(const u16x4*)(xbc + (unsigned)of0.x);
        cur[1] = *(const u16x4*)(xbc + (unsigned)of0.y);
        cur[2] = *(const u16x4*)(xbc + (unsigned)of0.z);
        cur[3] = *(const u16x4*)(xbc + (unsigned)of0.w);
    }

    for (int t = 0; t < degv; ++t) {
        {
            int4 ofn = *(const int4*)&nbrs_t[t + 1][grp * 4];   // sentinel-safe
            nxt[0] = *(const u16x4*)(xbc + (unsigned)ofn.x);
            nxt[1] = *(const u16x4*)(xbc + (unsigned)ofn.y);
            nxt[2] = *(const u16x4*)(xbc + (unsigned)ofn.z);
            nxt[3] = *(const u16x4*)(xbc + (unsigned)ofn.w);
        }
        f32x4 acc[4];
#pragma unroll
        for (int j = 0; j < 4; ++j)
#pragma unroll
            for (int q = 0; q < 4; ++q)
                acc[j][q] = bf2f(cur[q][j]);

        if (t > 0) {
            const char* hrd = (const char*)hbuf[t & 1];
#pragma unroll
            for (int kt = 0; kt < 4; ++kt) {
                s16x8 ah = *(const s16x8*)(hrd + rbyte[kt]);
#pragma unroll
                for (int j = 0; j < 4; ++j)
                    acc[j] = __builtin_amdgcn_mfma_f32_16x16x32_bf16(ah, breg[j][kt], acc[j], 0, 0, 0);
            }
        }
        // exp2-domain shared-rcp activations
        char* hwr = (char*)hbuf[(t + 1) & 1];
        {
            f32x4 Av, Bv, Cv, Dv;
#pragma unroll
            for (int q = 0; q < 4; ++q) {
                Av[q] = __builtin_amdgcn_exp2f(-acc[0][q]);
                Bv[q] = __builtin_amdgcn_exp2f(-acc[1][q]);
                Cv[q] = __builtin_amdgcn_exp2f(acc[2][q]);
                Dv[q] = __builtin_amdgcn_exp2f(-acc[3][q]);
            }
            f32x4 d1 = (Av + 1.0f) * (Cv + 1.0f);
            f32x4 d2 = Bv + 1.0f;
            f32x4 r1, r2;
#pragma unroll
            for (int q = 0; q < 4; ++q) {
                r1[q] = __builtin_amdgcn_rcpf(d1[q]);
                r2[q] = __builtin_amdgcn_rcpf(d2[q]);
            }
            f32x4 cv = cst * r2 + (Cv - 1.0f) * r1;
            cst = cv;
            f32x4 ecv = cv * TWO_L2E;
            f32x4 Ev;
#pragma unroll
            for (int q = 0; q < 4; ++q) Ev[q] = __builtin_amdgcn_exp2f(ecv[q]);
            f32x4 d3 = (Dv + 1.0f) * (Ev + 1.0f);
            f32x4 r3;
#pragma unroll
            for (int q = 0; q < 4; ++q) r3[q] = __builtin_amdgcn_rcpf(d3[q]);
            f32x4 hvv = (Ev - 1.0f) * r3;
#pragma unroll
            for (int q = 0; q < 4; ++q)
                *(unsigned short*)(hwr + wbyte[q]) = f2bf(hvv[q]);
        }
#pragma unroll
        for (int q = 0; q < 4; ++q) cur[q] = nxt[q];
        __syncthreads();
    }
    // write h_fin from hbuf[degv & 1]: 16 rows x 256B, 8B per thread
    const char* hf = (const char*)hbuf[degv & 1];
    int row = tid >> 5;
    int nd = nodes[row];
    if (nd >= 0) {
        int off = (tid & 31) * 8;
        int byte = (row * 256 + off) ^ ((row & 7) << 4);
        u16x4 v = *(const u16x4*)(hf + byte);
        *(u16x4*)(hfin + (size_t)nd * FF + off / 2) = v;
    }
}

// ---------------- projection: persistent, weights in registers --------------
// grid (160, 8): y = r*2+half; block preloads half the relation's Ws/Wn frags
// (32 frags = 128 regs) once, then loops over all 64-node chunks.
#define PROJ_BLOCKS_X 160
__global__ __launch_bounds__(256, 2) void k_projh(const unsigned short* __restrict__ fbf,
                                                  const unsigned short* __restrict__ hfin4,
                                                  const unsigned short* __restrict__ wstb,
                                                  const unsigned short* __restrict__ wntb,
                                                  const float* __restrict__ bo,
                                                  const int* __restrict__ D0, const int* __restrict__ D1,
                                                  const int* __restrict__ D2, const int* __restrict__ D3,
                                                  unsigned short* __restrict__ tmp) {
    int r = blockIdx.y >> 1;
    int half = blockIdx.y & 1;
    const int* dg = (r == 0) ? D0 : (r == 1) ? D1 : (r == 2) ? D2 : D3;
    int wv = threadIdx.x >> 6, l = threadIdx.x & 63;
    int col = l & 15, grp = l >> 4;

    // preload this half's weight frags: tiles half*4+tt, tt=0..3
    const unsigned short* wsb = wstb + (size_t)r * OO * FF + col * FF + grp * 8;
    const unsigned short* wnb = wntb + (size_t)r * OO * FF + col * FF + grp * 8;
    s16x8 bws[4][4], bwn[4][4];
#pragma unroll
    for (int tt = 0; tt < 4; ++tt)
#pragma unroll
        for (int kt = 0; kt < 4; ++kt) {
            size_t toff = (size_t)((half * 4 + tt) * 16) * FF + kt * 32;
            bws[tt][kt] = *(const s16x8*)(wsb + toff);
            bwn[tt][kt] = *(const s16x8*)(wnb + toff);
        }
    float bias[4];
#pragma unroll
    for (int tt = 0; tt < 4; ++tt) bias[tt] = bo[r * OO + (half * 4 + tt) * 16 + col];

    const unsigned short* hbase = hfin4 + (size_t)r * NN * FF;
    unsigned short* tp = tmp + (size_t)r * NN * OO;
    const s16x8 zfrag = {0, 0, 0, 0, 0, 0, 0, 0};

    for (int c = blockIdx.x; c < 625; c += PROJ_BLOCKS_X) {
        int n0 = c * 64 + wv * 16;
        s16x8 af[4], ah[4];
        const unsigned short* fp = fbf + (size_t)(n0 + col) * FF + grp * 8;
        const unsigned short* hp = hbase + (size_t)(n0 + col) * FF + grp * 8;
        int dval = dg[n0 + col];
#pragma unroll
        for (int kt = 0; kt < 4; ++kt) {
            af[kt] = *(const s16x8*)(fp + kt * 32);
            s16x8 h = *(const s16x8*)(hp + kt * 32);
            ah[kt] = (dval > 0) ? h : zfrag;
        }
        f32x4 acc[4];
#pragma unroll
        for (int tt = 0; tt < 4; ++tt) acc[tt] = splat4(bias[tt]);
#pragma unroll
        for (int kt = 0; kt < 4; ++kt) {
#pragma unroll
            for (int tt = 0; tt < 4; ++tt) {
                acc[tt] = __builtin_amdgcn_mfma_f32_16x16x32_bf16(af[kt], bws[tt][kt], acc[tt], 0, 0, 0);
                acc[tt] = __builtin_amdgcn_mfma_f32_16x16x32_bf16(ah[kt], bwn[tt][kt], acc[tt], 0, 0, 0);
            }
        }
#pragma unroll
        for (int q = 0; q < 4; ++q) {
            int node = n0 + grp * 4 + q;
#pragma unroll
            for (int tt = 0; tt < 4; ++tt)
                tp[node * OO + (half * 4 + tt) * 16 + col] = f2bf(acc[tt][q]);
        }
    }
}

// ---------------- combine: out = mean[seg] + max(p0,p1) + max(p2,p3) ---------
__global__ void k_combine(const unsigned short* __restrict__ tmp,
                          const float* __restrict__ mean, const int* __restrict__ seg,
                          float* __restrict__ out) {
    int i = blockIdx.x * blockDim.x + threadIdx.x;
    int idx4 = i * 4;
    if (idx4 >= NN * OO) return;
    int node = idx4 >> 7;
    int dim = idx4 & 127;
    ushort4 p0 = *(const ushort4*)(tmp + idx4);
    ushort4 p1 = *(const ushort4*)(tmp + (size_t)NN * OO + idx4);
    ushort4 p2 = *(const ushort4*)(tmp + 2 * (size_t)NN * OO + idx4);
    ushort4 p3 = *(const ushort4*)(tmp + 3 * (size_t)NN * OO + idx4);
    float4 mv = *(const float4*)(mean + seg[node] * FF + dim);
    float4 o;
    o.x = mv.x + fmaxf(bf2f(p0.x), bf2f(p1.x)) + fmaxf(bf2f(p2.x), bf2f(p3.x));
    o.y = mv.y + fmaxf(bf2f(p0.y), bf2f(p1.y)) + fmaxf(bf2f(p2.y), bf2f(p3.y));
    o.z = mv.z + fmaxf(bf2f(p0.z), bf2f(p1.z)) + fmaxf(bf2f(p2.z), bf2f(p3.z));
    o.w = mv.w + fmaxf(bf2f(p0.w), bf2f(p1.w)) + fmaxf(bf2f(p2.w), bf2f(p3.w));
    *(float4*)(out + idx4) = o;
}

extern "C" void kernel_launch(void* const* d_in, const int* in_sizes, int n_in,
                              void* d_out, int out_size, void* d_ws, size_t ws_size,
                              hipStream_t stream) {
    const float* feat = (const float*)d_in[0];
    const int* nbr[4] = {(const int*)d_in[1], (const int*)d_in[3], (const int*)d_in[5], (const int*)d_in[7]};
    const int* dgp[4] = {(const int*)d_in[2], (const int*)d_in[4], (const int*)d_in[6], (const int*)d_in[8]};
    const int* seg   = (const int*)d_in[9];
    const float* Wih = (const float*)d_in[10];
    const float* Whh = (const float*)d_in[11];
    const float* lb  = (const float*)d_in[12];
    const float* Ws  = (const float*)d_in[13];
    const float* Wn  = (const float*)d_in[14];
    const float* bo  = (const float*)d_in[15];

    char* ws = (char*)d_ws;
    float*          mean  = (float*)(ws + 0);                      //     32,768
    unsigned short* fbf   = (unsigned short*)(ws + 32768);         // 10,240,000
    unsigned short* wihb  = (unsigned short*)(ws + 10272768);      //    524,288
    unsigned short* whhb  = (unsigned short*)(ws + 10797056);      //    524,288
    unsigned short* wstb  = (unsigned short*)(ws + 11321344);      //    131,072
    unsigned short* wntb  = (unsigned short*)(ws + 11452416);      //    131,072
    unsigned short* xih   = (unsigned short*)(ws + 11583488);      // 4x or 1x 40,960,000

    const int big = (ws_size >= 217039872ULL);
    size_t xih_bytes = big ? 163840000ULL : 40960000ULL;
    unsigned short* hfin4 = (unsigned short*)(ws + 11583488 + xih_bytes);          // 40,960,000
    int*            order4= (int*)(ws + 11583488 + xih_bytes + 40960000);          //    655,360
    int*            cnt4  = (int*)(ws + 11583488 + xih_bytes + 40960000 + 655360); //      1,024
    unsigned short* tmp   = xih;   // xih dead after lstm; 40,960,000 B for 4 bf16 partials

    hipMemsetAsync(order4, 0xFF, 655360, stream);
    hipMemsetAsync(cnt4, 0, 1024, stream);

    k_prep<<<1024, 256, 0, stream>>>(Wih, Whh, Ws, Wn, feat, wihb, whhb, wstb, wntb, fbf);
    k_segmean<<<64, 512, 0, stream>>>(feat, seg, mean);
    k_count<<<dim3(157, 4), 256, 0, stream>>>(dgp[0], dgp[1], dgp[2], dgp[3], cnt4);
    k_offsets<<<1, 64, 0, stream>>>(cnt4);
    k_scatter<<<dim3(157, 4), 256, 0, stream>>>(dgp[0], dgp[1], dgp[2], dgp[3], cnt4, order4);

    if (big) {
        k_xih<<<dim3(1250, 4), 256, 0, stream>>>(fbf, wihb, lb, xih, 0);
        k_lstm<<<dim3(LSTM_BLOCKS, 4), 512, 0, stream>>>(xih, whhb, order4,
                                                         nbr[0], nbr[1], nbr[2], nbr[3],
                                                         dgp[0], dgp[1], dgp[2], dgp[3], hfin4, 0);
    } else {
        for (int r = 0; r < 4; ++r) {
            k_xih<<<dim3(1250, 1), 256, 0, stream>>>(fbf, wihb, lb, xih, r);
            k_lstm<<<dim3(LSTM_BLOCKS, 1), 512, 0, stream>>>(xih, whhb, order4,
                                                             nbr[0], nbr[1], nbr[2], nbr[3],
                                                             dgp[0], dgp[1], dgp[2], dgp[3], hfin4, r);
        }
    }
    k_projh<<<dim3(PROJ_BLOCKS_X, 8), 256, 0, stream>>>(fbf, hfin4, wstb, wntb, bo,
                                                        dgp[0], dgp[1], dgp[2], dgp[3], tmp);
    k_combine<<<5000, 256, 0, stream>>>(tmp, mean, seg, (float*)d_out);
}

// Round 13
// 426.759 us; speedup vs baseline: 1.3925x; 1.2066x over previous
//
#include <hip/hip_runtime.h>

#define NN 40000
#define DDEG 16
#define FF 128
#define OO 128
#define NG 512   // 4*F gates
#define XIH_ELEMS 20480000   // NN*NG u16 per relation
#define L2E 1.4426950408889634f
#define TWO_L2E 2.8853900817779268f

typedef short  s16x8 __attribute__((ext_vector_type(8)));
typedef unsigned short u16x8 __attribute__((ext_vector_type(8)));
typedef unsigned short u16x4 __attribute__((ext_vector_type(4)));
typedef float  f32x4 __attribute__((ext_vector_type(4)));

static_assert(sizeof(s16x8) == 16, "frag size");

__device__ __forceinline__ unsigned short f2bf(float f) {
    unsigned int u = __builtin_bit_cast(unsigned int, f);
    u += 0x7FFFu + ((u >> 16) & 1u);   // RNE
    return (unsigned short)(u >> 16);
}
__device__ __forceinline__ float bf2f(unsigned short s) {
    unsigned int u = ((unsigned int)s) << 16;
    return __builtin_bit_cast(float, u);
}
__device__ __forceinline__ f32x4 splat4(float v) { f32x4 r = {v, v, v, v}; return r; }

// ---- prep: weights -> bf16 with exp2 prescale; Ws/Wn transpose; feat cast ----
// gate-row scale: rows [0,256)+[384,512) (i,f,o): log2e; rows [256,384) (g): 2*log2e
__global__ void k_prep(const float* __restrict__ Wih, const float* __restrict__ Whh,
                       const float* __restrict__ Ws,  const float* __restrict__ Wn,
                       const float* __restrict__ feat,
                       unsigned short* __restrict__ wihb, unsigned short* __restrict__ whhb,
                       unsigned short* __restrict__ wstb, unsigned short* __restrict__ wntb,
                       unsigned short* __restrict__ fbf) {
    int i = blockIdx.x * blockDim.x + threadIdx.x;
    int stride = gridDim.x * blockDim.x;
    for (int idx = i; idx < 4 * NG * FF; idx += stride) {
        int row = (idx >> 7) & 511;
        float s = ((row >> 7) == 2) ? TWO_L2E : L2E;
        wihb[idx] = f2bf(Wih[idx] * s);
        whhb[idx] = f2bf(Whh[idx] * s);
    }
    for (int idx = i; idx < 4 * FF * OO; idx += stride) {
        int r = idx >> 14;
        int rem = idx & 16383;
        int o = rem >> 7;
        int k = rem & 127;
        wstb[idx] = f2bf(Ws[(r << 14) + (k << 7) + o]);
        wntb[idx] = f2bf(Wn[(r << 14) + (k << 7) + o]);
    }
    for (int idx4 = i * 4; idx4 < NN * FF; idx4 += stride * 4) {
        float4 v = *(const float4*)(feat + idx4);
        ushort4 o;
        o.x = f2bf(v.x); o.y = f2bf(v.y); o.z = f2bf(v.z); o.w = f2bf(v.w);
        *(ushort4*)(fbf + idx4) = o;
    }
}

// ---------------- segment mean (seg_ids sorted, G=64), 512 thr ---------------
__global__ void k_segmean(const float* __restrict__ feat, const int* __restrict__ seg,
                          float* __restrict__ mean) {
    int g = blockIdx.x;
    int lo, hi;
    { int a = 0, b = NN; while (a < b) { int m = (a + b) >> 1; if (seg[m] < g) a = m + 1; else b = m; } lo = a; }
    { int a = 0, b = NN; while (a < b) { int m = (a + b) >> 1; if (seg[m] < g + 1) a = m + 1; else b = m; } hi = a; }
    int tid = threadIdx.x;
    int d4 = tid & 31;          // float4 slot
    int part = tid >> 5;        // 16 row-partitions
    float4 s = {0.f, 0.f, 0.f, 0.f};
    for (int row = lo + part; row < hi; row += 16) {
        float4 v = *(const float4*)(feat + (size_t)row * FF + d4 * 4);
        s.x += v.x; s.y += v.y; s.z += v.z; s.w += v.w;
    }
    __shared__ float ps[16][128];
    ps[part][d4 * 4 + 0] = s.x; ps[part][d4 * 4 + 1] = s.y;
    ps[part][d4 * 4 + 2] = s.z; ps[part][d4 * 4 + 3] = s.w;
    __syncthreads();
    if (tid < 128) {
        float tot = 0.f;
#pragma unroll
        for (int p = 0; p < 16; ++p) tot += ps[p][tid];
        mean[g * FF + tid] = tot / fmaxf((float)(hi - lo), 1.0f);
    }
}

// ---------------- deg bucketing, all 4 relations (two-level histogram) -------
__global__ void k_count(const int* __restrict__ D0, const int* __restrict__ D1,
                        const int* __restrict__ D2, const int* __restrict__ D3,
                        int* __restrict__ cnt4) {
    int r = blockIdx.y;
    const int* dg = (r == 0) ? D0 : (r == 1) ? D1 : (r == 2) ? D2 : D3;
    __shared__ int lcnt[17];
    if (threadIdx.x < 17) lcnt[threadIdx.x] = 0;
    __syncthreads();
    int n = blockIdx.x * blockDim.x + threadIdx.x;
    if (n < NN) { int d = dg[n]; if (d > 0) atomicAdd(&lcnt[d], 1); }
    __syncthreads();
    if (threadIdx.x >= 1 && threadIdx.x < 17 && lcnt[threadIdx.x])
        atomicAdd(&cnt4[r * 64 + threadIdx.x], lcnt[threadIdx.x]);
}
__global__ void k_offsets(int* __restrict__ cnt4) {
    int r = threadIdx.x;
    if (r < 4 && blockIdx.x == 0) {
        int running = 0;
        for (int d = 16; d >= 1; --d) {
            cnt4[r * 64 + 40 + d] = running;
            running += (cnt4[r * 64 + d] + 15) & ~15;
        }
    }
}
__global__ void k_scatter(const int* __restrict__ D0, const int* __restrict__ D1,
                          const int* __restrict__ D2, const int* __restrict__ D3,
                          int* __restrict__ cnt4, int* __restrict__ order4) {
    int r = blockIdx.y;
    const int* dg = (r == 0) ? D0 : (r == 1) ? D1 : (r == 2) ? D2 : D3;
    __shared__ int lcnt[17];
    __shared__ int gbase[17];
    if (threadIdx.x < 17) lcnt[threadIdx.x] = 0;
    __syncthreads();
    int n = blockIdx.x * blockDim.x + threadIdx.x;
    int d = 0, rank = 0;
    if (n < NN) { d = dg[n]; if (d > 0) rank = atomicAdd(&lcnt[d], 1); }
    __syncthreads();
    if (threadIdx.x >= 1 && threadIdx.x < 17 && lcnt[threadIdx.x])
        gbase[threadIdx.x] = atomicAdd(&cnt4[r * 64 + 40 + threadIdx.x], lcnt[threadIdx.x]);
    __syncthreads();
    if (n < NN && d > 0) order4[r * 40960 + gbase[d] + rank] = n;
}

// ---------------- Xih: persistent, Wih in registers --------------------------
// grid (128, 4): wave w owns tiles {w+4j, j=0..7} = 32 frags = 128 regs,
// preloaded once; loop over 16-node chunks. Output layout: u16 index
// (T&7)*64 + col*4 + (T>>3) for gate-tile T.
#define XIH_BLOCKS_X 128
__global__ __launch_bounds__(256, 2) void k_xih(const unsigned short* __restrict__ fbf,
                                                const unsigned short* __restrict__ wihb,
                                                const float* __restrict__ lb,
                                                unsigned short* __restrict__ xih, int rbase) {
    int r = rbase + blockIdx.y;
    unsigned short* xr = xih + (size_t)blockIdx.y * XIH_ELEMS;
    int tid = threadIdx.x;
    int w = tid >> 6;
    int l = tid & 63;
    int col = l & 15, grp = l >> 4;

    // preload Wih slice (loop-invariant): tiles {w+4j}
    const unsigned short* wb = wihb + (size_t)r * NG * FF + col * FF + grp * 8;
    s16x8 bx[8][4];
#pragma unroll
    for (int j = 0; j < 8; ++j)
#pragma unroll
        for (int kt = 0; kt < 4; ++kt)
            bx[j][kt] = *(const s16x8*)(wb + (size_t)(w + 4 * j) * 16 * FF + kt * 32);

    float bias[8];
#pragma unroll
    for (int j = 0; j < 8; ++j) {
        float sc = (((w + 4 * j) >> 3) == 2) ? TWO_L2E : L2E;
        bias[j] = lb[r * NG + (w + 4 * j) * 16 + col] * sc;
    }

    for (int c = blockIdx.x; c < 2500; c += XIH_BLOCKS_X) {
        int n0 = c * 16;
        s16x8 a[4];
        const unsigned short* ap = fbf + (size_t)(n0 + col) * FF + grp * 8;
#pragma unroll
        for (int kt = 0; kt < 4; ++kt) a[kt] = *(const s16x8*)(ap + kt * 32);

        f32x4 acc[8];
#pragma unroll
        for (int j = 0; j < 8; ++j) acc[j] = splat4(bias[j]);
#pragma unroll
        for (int j = 0; j < 8; ++j)
#pragma unroll
            for (int kt = 0; kt < 4; ++kt)
                acc[j] = __builtin_amdgcn_mfma_f32_16x16x32_bf16(a[kt], bx[j][kt], acc[j], 0, 0, 0);

        // store: tile T=w+4j -> u16 idx (T&7)*64+col*4+(T>>3); j even -> slot w, odd -> w+4
#pragma unroll
        for (int q = 0; q < 4; ++q) {
            int node = n0 + grp * 4 + q;
            u16x4 ue, uo;
#pragma unroll
            for (int m = 0; m < 4; ++m) {
                ue[m] = f2bf(acc[2 * m][q]);
                uo[m] = f2bf(acc[2 * m + 1][q]);
            }
            *(u16x4*)(xr + (size_t)node * NG + w * 64 + col * 4) = ue;
            *(u16x4*)(xr + (size_t)node * NG + (w + 4) * 64 + col * 4) = uo;
        }
    }
}

// ---------------- bucketed LSTM: 8 waves x 4 tiles, Whh in regs --------------
// r11-measured configuration (321 us/dispatch): 1280 blocks x 2 groups; wave w
// owns tiles {w+8j}; transposed nbr table (ds_read_b128); single-step register
// prefetch; exp2-domain shared-rcp f32x4 activations; manual RNE f2bf.
#define LSTM_BLOCKS 1280
#define LSTM_GROUPS 2
__global__ __launch_bounds__(512, 4) void k_lstm(const unsigned short* __restrict__ xih,
                                                 const unsigned short* __restrict__ whhb,
                                                 const int* __restrict__ order4,
                                                 const int* __restrict__ N0, const int* __restrict__ N1,
                                                 const int* __restrict__ N2, const int* __restrict__ N3,
                                                 const int* __restrict__ D0, const int* __restrict__ D1,
                                                 const int* __restrict__ D2, const int* __restrict__ D3,
                                                 unsigned short* __restrict__ hfin4, int rbase) {
    int r = rbase + blockIdx.y;
    const unsigned short* xr = xih + (size_t)blockIdx.y * XIH_ELEMS;
    const int* nbr = (r == 0) ? N0 : (r == 1) ? N1 : (r == 2) ? N2 : N3;
    const int* deg = (r == 0) ? D0 : (r == 1) ? D1 : (r == 2) ? D2 : D3;
    const int* order = order4 + r * 40960;
    unsigned short* hfin = hfin4 + (size_t)r * NN * FF;

    __shared__ int nodes[16];
    __shared__ int nbrs_t[16][16];             // [t][node]: premultiplied byte offsets
    __shared__ unsigned short hbuf[2][2048];   // 2 x (16 rows x 128 dims bf16), XOR-swizzled
    int tid = threadIdx.x;
    int w = tid >> 6, l = tid & 63;
    int col = l & 15, grp = l >> 4;

    // Whh slice: tiles {w+8j}, 16 frags = 64 regs
    const unsigned short* whhp = whhb + (size_t)r * NG * FF + col * FF + grp * 8;
    s16x8 breg[4][4];
#pragma unroll
    for (int j = 0; j < 4; ++j)
#pragma unroll
        for (int kt = 0; kt < 4; ++kt)
            breg[j][kt] = *(const s16x8*)(whhp + (size_t)(w + 8 * j) * 16 * FF + kt * 32);

    const char* xbc = (const char*)(xr + w * 64 + col * 4);

    int rbyte[4];
#pragma unroll
    for (int kt = 0; kt < 4; ++kt)
        rbyte[kt] = (col * 256 + kt * 64 + grp * 16) ^ ((col & 7) << 4);
    int wbyte[4];
#pragma unroll
    for (int q = 0; q < 4; ++q) {
        int node = grp * 4 + q;
        wbyte[q] = (node * 256 + (w * 16 + col) * 2) ^ ((node & 7) << 4);
    }

    for (int gi = 0; gi < LSTM_GROUPS; ++gi) {
        int g0 = (blockIdx.x + gi * LSTM_BLOCKS) * 16;
        __syncthreads();
        if (tid < 16) nodes[tid] = order[g0 + tid];
        __syncthreads();
        if (nodes[0] < 0) continue;          // uniform
        int degv = deg[nodes[0]];

        if (tid < 256) {
            int row = tid >> 4, t = tid & 15;   // global read stays node-coalesced
            int nd = nodes[row]; if (nd < 0) nd = 0;
            nbrs_t[t][row] = nbr[nd * DDEG + t] << 10;
        }
        __syncthreads();

        f32x4 cst = splat4(0.f);

        u16x4 cur[4], nxt[4];
        {
            int4 of0 = *(const int4*)&nbrs_t[0][grp * 4];
            cur[0] = *(const u16x4*)(xbc + (unsigned)of0.x);
            cur[1] = *(const u16x4*)(xbc + (unsigned)of0.y);
            cur[2] = *(const u16x4*)(xbc + (unsigned)of0.z);
            cur[3] = *(const u16x4*)(xbc + (unsigned)of0.w);
        }

        for (int t = 0; t < degv; ++t) {
            if (t + 1 < degv) {
                int4 ofn = *(const int4*)&nbrs_t[t + 1][grp * 4];
                nxt[0] = *(const u16x4*)(xbc + (unsigned)ofn.x);
                nxt[1] = *(const u16x4*)(xbc + (unsigned)ofn.y);
                nxt[2] = *(const u16x4*)(xbc + (unsigned)ofn.z);
                nxt[3] = *(const u16x4*)(xbc + (unsigned)ofn.w);
            }
            f32x4 acc[4];
#pragma unroll
            for (int j = 0; j < 4; ++j)
#pragma unroll
                for (int q = 0; q < 4; ++q)
                    acc[j][q] = bf2f(cur[q][j]);

            if (t > 0) {
                const char* hrd = (const char*)hbuf[t & 1];
#pragma unroll
                for (int kt = 0; kt < 4; ++kt) {
                    s16x8 ah = *(const s16x8*)(hrd + rbyte[kt]);
#pragma unroll
                    for (int j = 0; j < 4; ++j)
                        acc[j] = __builtin_amdgcn_mfma_f32_16x16x32_bf16(ah, breg[j][kt], acc[j], 0, 0, 0);
                }
            }
            // exp2-domain shared-rcp activations, f32x4 arithmetic
            char* hwr = (char*)hbuf[(t + 1) & 1];
            {
                f32x4 Av, Bv, Cv, Dv;
#pragma unroll
                for (int q = 0; q < 4; ++q) {
                    Av[q] = __builtin_amdgcn_exp2f(-acc[0][q]);
                    Bv[q] = __builtin_amdgcn_exp2f(-acc[1][q]);
                    Cv[q] = __builtin_amdgcn_exp2f(acc[2][q]);
                    Dv[q] = __builtin_amdgcn_exp2f(-acc[3][q]);
                }
                f32x4 d1 = (Av + 1.0f) * (Cv + 1.0f);
                f32x4 d2 = Bv + 1.0f;
                f32x4 r1, r2;
#pragma unroll
                for (int q = 0; q < 4; ++q) {
                    r1[q] = __builtin_amdgcn_rcpf(d1[q]);
                    r2[q] = __builtin_amdgcn_rcpf(d2[q]);
                }
                f32x4 cv = cst * r2 + (Cv - 1.0f) * r1;
                cst = cv;
                f32x4 ecv = cv * TWO_L2E;
                f32x4 Ev;
#pragma unroll
                for (int q = 0; q < 4; ++q) Ev[q] = __builtin_amdgcn_exp2f(ecv[q]);
                f32x4 d3 = (Dv + 1.0f) * (Ev + 1.0f);
                f32x4 r3;
#pragma unroll
                for (int q = 0; q < 4; ++q) r3[q] = __builtin_amdgcn_rcpf(d3[q]);
                f32x4 hvv = (Ev - 1.0f) * r3;
#pragma unroll
                for (int q = 0; q < 4; ++q)
                    *(unsigned short*)(hwr + wbyte[q]) = f2bf(hvv[q]);
            }
#pragma unroll
            for (int q = 0; q < 4; ++q) cur[q] = nxt[q];
            __syncthreads();
        }
        // write h_fin from hbuf[degv & 1]: 16 rows x 256B, 8B per thread
        const char* hf = (const char*)hbuf[degv & 1];
        int row = tid >> 5;
        int nd = nodes[row];
        if (nd >= 0) {
            int off = (tid & 31) * 8;
            int byte = (row * 256 + off) ^ ((row & 7) << 4);
            u16x4 v = *(const u16x4*)(hf + byte);
            *(u16x4*)(hfin + (size_t)nd * FF + off / 2) = v;
        }
    }
}

// ---------------- projection: persistent, weights in registers --------------
#define PROJ_BLOCKS_X 160
__global__ __launch_bounds__(256, 2) void k_projh(const unsigned short* __restrict__ fbf,
                                                  const unsigned short* __restrict__ hfin4,
                                                  const unsigned short* __restrict__ wstb,
                                                  const unsigned short* __restrict__ wntb,
                                                  const float* __restrict__ bo,
                                                  const int* __restrict__ D0, const int* __restrict__ D1,
                                                  const int* __restrict__ D2, const int* __restrict__ D3,
                                                  unsigned short* __restrict__ tmp) {
    int r = blockIdx.y >> 1;
    int half = blockIdx.y & 1;
    const int* dg = (r == 0) ? D0 : (r == 1) ? D1 : (r == 2) ? D2 : D3;
    int wv = threadIdx.x >> 6, l = threadIdx.x & 63;
    int col = l & 15, grp = l >> 4;

    const unsigned short* wsb = wstb + (size_t)r * OO * FF + col * FF + grp * 8;
    const unsigned short* wnb = wntb + (size_t)r * OO * FF + col * FF + grp * 8;
    s16x8 bws[4][4], bwn[4][4];
#pragma unroll
    for (int tt = 0; tt < 4; ++tt)
#pragma unroll
        for (int kt = 0; kt < 4; ++kt) {
            size_t toff = (size_t)((half * 4 + tt) * 16) * FF + kt * 32;
            bws[tt][kt] = *(const s16x8*)(wsb + toff);
            bwn[tt][kt] = *(const s16x8*)(wnb + toff);
        }
    float bias[4];
#pragma unroll
    for (int tt = 0; tt < 4; ++tt) bias[tt] = bo[r * OO + (half * 4 + tt) * 16 + col];

    const unsigned short* hbase = hfin4 + (size_t)r * NN * FF;
    unsigned short* tp = tmp + (size_t)r * NN * OO;
    const s16x8 zfrag = {0, 0, 0, 0, 0, 0, 0, 0};

    for (int c = blockIdx.x; c < 625; c += PROJ_BLOCKS_X) {
        int n0 = c * 64 + wv * 16;
        s16x8 af[4], ah[4];
        const unsigned short* fp = fbf + (size_t)(n0 + col) * FF + grp * 8;
        const unsigned short* hp = hbase + (size_t)(n0 + col) * FF + grp * 8;
        int dval = dg[n0 + col];
#pragma unroll
        for (int kt = 0; kt < 4; ++kt) {
            af[kt] = *(const s16x8*)(fp + kt * 32);
            s16x8 h = *(const s16x8*)(hp + kt * 32);
            ah[kt] = (dval > 0) ? h : zfrag;
        }
        f32x4 acc[4];
#pragma unroll
        for (int tt = 0; tt < 4; ++tt) acc[tt] = splat4(bias[tt]);
#pragma unroll
        for (int kt = 0; kt < 4; ++kt) {
#pragma unroll
            for (int tt = 0; tt < 4; ++tt) {
                acc[tt] = __builtin_amdgcn_mfma_f32_16x16x32_bf16(af[kt], bws[tt][kt], acc[tt], 0, 0, 0);
                acc[tt] = __builtin_amdgcn_mfma_f32_16x16x32_bf16(ah[kt], bwn[tt][kt], acc[tt], 0, 0, 0);
            }
        }
#pragma unroll
        for (int q = 0; q < 4; ++q) {
            int node = n0 + grp * 4 + q;
#pragma unroll
            for (int tt = 0; tt < 4; ++tt)
                tp[node * OO + (half * 4 + tt) * 16 + col] = f2bf(acc[tt][q]);
        }
    }
}

// ---------------- combine: out = mean[seg] + max(p0,p1) + max(p2,p3) ---------
__global__ void k_combine(const unsigned short* __restrict__ tmp,
                          const float* __restrict__ mean, const int* __restrict__ seg,
                          float* __restrict__ out) {
    int i = blockIdx.x * blockDim.x + threadIdx.x;
    int idx4 = i * 4;
    if (idx4 >= NN * OO) return;
    int node = idx4 >> 7;
    int dim = idx4 & 127;
    ushort4 p0 = *(const ushort4*)(tmp + idx4);
    ushort4 p1 = *(const ushort4*)(tmp + (size_t)NN * OO + idx4);
    ushort4 p2 = *(const ushort4*)(tmp + 2 * (size_t)NN * OO + idx4);
    ushort4 p3 = *(const ushort4*)(tmp + 3 * (size_t)NN * OO + idx4);
    float4 mv = *(const float4*)(mean + seg[node] * FF + dim);
    float4 o;
    o.x = mv.x + fmaxf(bf2f(p0.x), bf2f(p1.x)) + fmaxf(bf2f(p2.x), bf2f(p3.x));
    o.y = mv.y + fmaxf(bf2f(p0.y), bf2f(p1.y)) + fmaxf(bf2f(p2.y), bf2f(p3.y));
    o.z = mv.z + fmaxf(bf2f(p0.z), bf2f(p1.z)) + fmaxf(bf2f(p2.z), bf2f(p3.z));
    o.w = mv.w + fmaxf(bf2f(p0.w), bf2f(p1.w)) + fmaxf(bf2f(p2.w), bf2f(p3.w));
    *(float4*)(out + idx4) = o;
}

extern "C" void kernel_launch(void* const* d_in, const int* in_sizes, int n_in,
                              void* d_out, int out_size, void* d_ws, size_t ws_size,
                              hipStream_t stream) {
    const float* feat = (const float*)d_in[0];
    const int* nbr[4] = {(const int*)d_in[1], (const int*)d_in[3], (const int*)d_in[5], (const int*)d_in[7]};
    const int* dgp[4] = {(const int*)d_in[2], (const int*)d_in[4], (const int*)d_in[6], (const int*)d_in[8]};
    const int* seg   = (const int*)d_in[9];
    const float* Wih = (const float*)d_in[10];
    const float* Whh = (const float*)d_in[11];
    const float* lb  = (const float*)d_in[12];
    const float* Ws  = (const float*)d_in[13];
    const float* Wn  = (const float*)d_in[14];
    const float* bo  = (const float*)d_in[15];

    char* ws = (char*)d_ws;
    float*          mean  = (float*)(ws + 0);                      //     32,768
    unsigned short* fbf   = (unsigned short*)(ws + 32768);         // 10,240,000
    unsigned short* wihb  = (unsigned short*)(ws + 10272768);      //    524,288
    unsigned short* whhb  = (unsigned short*)(ws + 10797056);      //    524,288
    unsigned short* wstb  = (unsigned short*)(ws + 11321344);      //    131,072
    unsigned short* wntb  = (unsigned short*)(ws + 11452416);      //    131,072
    unsigned short* xih   = (unsigned short*)(ws + 11583488);      // 4x or 1x 40,960,000

    const int big = (ws_size >= 217039872ULL);
    size_t xih_bytes = big ? 163840000ULL : 40960000ULL;
    unsigned short* hfin4 = (unsigned short*)(ws + 11583488 + xih_bytes);          // 40,960,000
    int*            order4= (int*)(ws + 11583488 + xih_bytes + 40960000);          //    655,360
    int*            cnt4  = (int*)(ws + 11583488 + xih_bytes + 40960000 + 655360); //      1,024
    unsigned short* tmp   = xih;   // xih dead after lstm; 40,960,000 B for 4 bf16 partials

    hipMemsetAsync(order4, 0xFF, 655360, stream);
    hipMemsetAsync(cnt4, 0, 1024, stream);

    k_prep<<<1024, 256, 0, stream>>>(Wih, Whh, Ws, Wn, feat, wihb, whhb, wstb, wntb, fbf);
    k_segmean<<<64, 512, 0, stream>>>(feat, seg, mean);
    k_count<<<dim3(157, 4), 256, 0, stream>>>(dgp[0], dgp[1], dgp[2], dgp[3], cnt4);
    k_offsets<<<1, 64, 0, stream>>>(cnt4);
    k_scatter<<<dim3(157, 4), 256, 0, stream>>>(dgp[0], dgp[1], dgp[2], dgp[3], cnt4, order4);

    if (big) {
        k_xih<<<dim3(XIH_BLOCKS_X, 4), 256, 0, stream>>>(fbf, wihb, lb, xih, 0);
        k_lstm<<<dim3(LSTM_BLOCKS, 4), 512, 0, stream>>>(xih, whhb, order4,
                                                         nbr[0], nbr[1], nbr[2], nbr[3],
                                                         dgp[0], dgp[1], dgp[2], dgp[3], hfin4, 0);
    } else {
        for (int r = 0; r < 4; ++r) {
            k_xih<<<dim3(XIH_BLOCKS_X, 1), 256, 0, stream>>>(fbf, wihb, lb, xih, r);
            k_lstm<<<dim3(LSTM_BLOCKS, 1), 512, 0, stream>>>(xih, whhb, order4,
                                                             nbr[0], nbr[1], nbr[2], nbr[3],
                                                             dgp[0], dgp[1], dgp[2], dgp[3], hfin4, r);
        }
    }
    k_projh<<<dim3(PROJ_BLOCKS_X, 8), 256, 0, stream>>>(fbf, hfin4, wstb, wntb, bo,
                                                        dgp[0], dgp[1], dgp[2], dgp[3], tmp);
    k_combine<<<5000, 256, 0, stream>>>(tmp, mean, seg, (float*)d_out);
}

// Round 14
// 416.725 us; speedup vs baseline: 1.4260x; 1.0241x over previous
//
#include <hip/hip_runtime.h>

#define NN 40000
#define DDEG 16
#define FF 128
#define OO 128
#define NG 512   // 4*F gates
#define XIH_ELEMS 20480000   // NN*NG u16 per relation
#define L2E 1.4426950408889634f
#define TWO_L2E 2.8853900817779268f

typedef short  s16x8 __attribute__((ext_vector_type(8)));
typedef unsigned short u16x8 __attribute__((ext_vector_type(8)));
typedef unsigned short u16x4 __attribute__((ext_vector_type(4)));
typedef float  f32x4 __attribute__((ext_vector_type(4)));

static_assert(sizeof(s16x8) == 16, "frag size");

__device__ __forceinline__ unsigned short f2bf(float f) {
    unsigned int u = __builtin_bit_cast(unsigned int, f);
    u += 0x7FFFu + ((u >> 16) & 1u);   // RNE
    return (unsigned short)(u >> 16);
}
__device__ __forceinline__ float bf2f(unsigned short s) {
    unsigned int u = ((unsigned int)s) << 16;
    return __builtin_bit_cast(float, u);
}
__device__ __forceinline__ f32x4 splat4(float v) { f32x4 r = {v, v, v, v}; return r; }

// ---- prep: weights -> bf16 with exp2 prescale; Ws/Wn transpose; feat cast ----
// gate-row scale: rows [0,256)+[384,512) (i,f,o): log2e; rows [256,384) (g): 2*log2e
__global__ void k_prep(const float* __restrict__ Wih, const float* __restrict__ Whh,
                       const float* __restrict__ Ws,  const float* __restrict__ Wn,
                       const float* __restrict__ feat,
                       unsigned short* __restrict__ wihb, unsigned short* __restrict__ whhb,
                       unsigned short* __restrict__ wstb, unsigned short* __restrict__ wntb,
                       unsigned short* __restrict__ fbf) {
    int i = blockIdx.x * blockDim.x + threadIdx.x;
    int stride = gridDim.x * blockDim.x;
    for (int idx = i; idx < 4 * NG * FF; idx += stride) {
        int row = (idx >> 7) & 511;
        float s = ((row >> 7) == 2) ? TWO_L2E : L2E;
        wihb[idx] = f2bf(Wih[idx] * s);
        whhb[idx] = f2bf(Whh[idx] * s);
    }
    for (int idx = i; idx < 4 * FF * OO; idx += stride) {
        int r = idx >> 14;
        int rem = idx & 16383;
        int o = rem >> 7;
        int k = rem & 127;
        wstb[idx] = f2bf(Ws[(r << 14) + (k << 7) + o]);
        wntb[idx] = f2bf(Wn[(r << 14) + (k << 7) + o]);
    }
    for (int idx4 = i * 4; idx4 < NN * FF; idx4 += stride * 4) {
        float4 v = *(const float4*)(feat + idx4);
        ushort4 o;
        o.x = f2bf(v.x); o.y = f2bf(v.y); o.z = f2bf(v.z); o.w = f2bf(v.w);
        *(ushort4*)(fbf + idx4) = o;
    }
}

// ---------------- segment mean (seg_ids sorted, G=64), 512 thr ---------------
__global__ void k_segmean(const float* __restrict__ feat, const int* __restrict__ seg,
                          float* __restrict__ mean) {
    int g = blockIdx.x;
    int lo, hi;
    { int a = 0, b = NN; while (a < b) { int m = (a + b) >> 1; if (seg[m] < g) a = m + 1; else b = m; } lo = a; }
    { int a = 0, b = NN; while (a < b) { int m = (a + b) >> 1; if (seg[m] < g + 1) a = m + 1; else b = m; } hi = a; }
    int tid = threadIdx.x;
    int d4 = tid & 31;          // float4 slot
    int part = tid >> 5;        // 16 row-partitions
    float4 s = {0.f, 0.f, 0.f, 0.f};
    for (int row = lo + part; row < hi; row += 16) {
        float4 v = *(const float4*)(feat + (size_t)row * FF + d4 * 4);
        s.x += v.x; s.y += v.y; s.z += v.z; s.w += v.w;
    }
    __shared__ float ps[16][128];
    ps[part][d4 * 4 + 0] = s.x; ps[part][d4 * 4 + 1] = s.y;
    ps[part][d4 * 4 + 2] = s.z; ps[part][d4 * 4 + 3] = s.w;
    __syncthreads();
    if (tid < 128) {
        float tot = 0.f;
#pragma unroll
        for (int p = 0; p < 16; ++p) tot += ps[p][tid];
        mean[g * FF + tid] = tot / fmaxf((float)(hi - lo), 1.0f);
    }
}

// ---------------- deg bucketing, all 4 relations (two-level histogram) -------
__global__ void k_count(const int* __restrict__ D0, const int* __restrict__ D1,
                        const int* __restrict__ D2, const int* __restrict__ D3,
                        int* __restrict__ cnt4) {
    int r = blockIdx.y;
    const int* dg = (r == 0) ? D0 : (r == 1) ? D1 : (r == 2) ? D2 : D3;
    __shared__ int lcnt[17];
    if (threadIdx.x < 17) lcnt[threadIdx.x] = 0;
    __syncthreads();
    int n = blockIdx.x * blockDim.x + threadIdx.x;
    if (n < NN) { int d = dg[n]; if (d > 0) atomicAdd(&lcnt[d], 1); }
    __syncthreads();
    if (threadIdx.x >= 1 && threadIdx.x < 17 && lcnt[threadIdx.x])
        atomicAdd(&cnt4[r * 64 + threadIdx.x], lcnt[threadIdx.x]);
}
__global__ void k_offsets(int* __restrict__ cnt4) {
    int r = threadIdx.x;
    if (r < 4 && blockIdx.x == 0) {
        int running = 0;
        for (int d = 16; d >= 1; --d) {
            cnt4[r * 64 + 40 + d] = running;
            running += (cnt4[r * 64 + d] + 15) & ~15;
        }
    }
}
__global__ void k_scatter(const int* __restrict__ D0, const int* __restrict__ D1,
                          const int* __restrict__ D2, const int* __restrict__ D3,
                          int* __restrict__ cnt4, int* __restrict__ order4) {
    int r = blockIdx.y;
    const int* dg = (r == 0) ? D0 : (r == 1) ? D1 : (r == 2) ? D2 : D3;
    __shared__ int lcnt[17];
    __shared__ int gbase[17];
    if (threadIdx.x < 17) lcnt[threadIdx.x] = 0;
    __syncthreads();
    int n = blockIdx.x * blockDim.x + threadIdx.x;
    int d = 0, rank = 0;
    if (n < NN) { d = dg[n]; if (d > 0) rank = atomicAdd(&lcnt[d], 1); }
    __syncthreads();
    if (threadIdx.x >= 1 && threadIdx.x < 17 && lcnt[threadIdx.x])
        gbase[threadIdx.x] = atomicAdd(&cnt4[r * 64 + 40 + threadIdx.x], lcnt[threadIdx.x]);
    __syncthreads();
    if (n < NN && d > 0) order4[r * 40960 + gbase[d] + rank] = n;
}

// ---------------- Xih: persistent, Wih in registers --------------------------
// grid (128, 4): wave w owns tiles {w+4j, j=0..7} = 32 frags = 128 regs,
// preloaded once; loop over 16-node chunks. Output layout: u16 index
// (T&7)*64 + col*4 + (T>>3) for gate-tile T.
#define XIH_BLOCKS_X 128
__global__ __launch_bounds__(256, 2) void k_xih(const unsigned short* __restrict__ fbf,
                                                const unsigned short* __restrict__ wihb,
                                                const float* __restrict__ lb,
                                                unsigned short* __restrict__ xih, int rbase) {
    int r = rbase + blockIdx.y;
    unsigned short* xr = xih + (size_t)blockIdx.y * XIH_ELEMS;
    int tid = threadIdx.x;
    int w = tid >> 6;
    int l = tid & 63;
    int col = l & 15, grp = l >> 4;

    // preload Wih slice (loop-invariant): tiles {w+4j}
    const unsigned short* wb = wihb + (size_t)r * NG * FF + col * FF + grp * 8;
    s16x8 bx[8][4];
#pragma unroll
    for (int j = 0; j < 8; ++j)
#pragma unroll
        for (int kt = 0; kt < 4; ++kt)
            bx[j][kt] = *(const s16x8*)(wb + (size_t)(w + 4 * j) * 16 * FF + kt * 32);

    float bias[8];
#pragma unroll
    for (int j = 0; j < 8; ++j) {
        float sc = (((w + 4 * j) >> 3) == 2) ? TWO_L2E : L2E;
        bias[j] = lb[r * NG + (w + 4 * j) * 16 + col] * sc;
    }

    for (int c = blockIdx.x; c < 2500; c += XIH_BLOCKS_X) {
        int n0 = c * 16;
        s16x8 a[4];
        const unsigned short* ap = fbf + (size_t)(n0 + col) * FF + grp * 8;
#pragma unroll
        for (int kt = 0; kt < 4; ++kt) a[kt] = *(const s16x8*)(ap + kt * 32);

        f32x4 acc[8];
#pragma unroll
        for (int j = 0; j < 8; ++j) acc[j] = splat4(bias[j]);
#pragma unroll
        for (int j = 0; j < 8; ++j)
#pragma unroll
            for (int kt = 0; kt < 4; ++kt)
                acc[j] = __builtin_amdgcn_mfma_f32_16x16x32_bf16(a[kt], bx[j][kt], acc[j], 0, 0, 0);

        // store: tile T=w+4j -> u16 idx (T&7)*64+col*4+(T>>3); j even -> slot w, odd -> w+4
#pragma unroll
        for (int q = 0; q < 4; ++q) {
            int node = n0 + grp * 4 + q;
            u16x4 ue, uo;
#pragma unroll
            for (int m = 0; m < 4; ++m) {
                ue[m] = f2bf(acc[2 * m][q]);
                uo[m] = f2bf(acc[2 * m + 1][q]);
            }
            *(u16x4*)(xr + (size_t)node * NG + w * 64 + col * 4) = ue;
            *(u16x4*)(xr + (size_t)node * NG + (w + 4) * 64 + col * 4) = uo;
        }
    }
}

// ---------------- bucketed LSTM: 8 waves x 4 tiles, Whh in regs --------------
// r13 structure with two address-path micro-opts: (1) gathers use block-uniform
// base (SGPR) + per-lane 32-bit offset (saddr form, 1 VALU add per gather);
// (2) sentinel row 16 in nbrs_t -> unconditional branchless prefetch.
#define LSTM_BLOCKS 1280
#define LSTM_GROUPS 2
__global__ __launch_bounds__(512, 4) void k_lstm(const unsigned short* __restrict__ xih,
                                                 const unsigned short* __restrict__ whhb,
                                                 const int* __restrict__ order4,
                                                 const int* __restrict__ N0, const int* __restrict__ N1,
                                                 const int* __restrict__ N2, const int* __restrict__ N3,
                                                 const int* __restrict__ D0, const int* __restrict__ D1,
                                                 const int* __restrict__ D2, const int* __restrict__ D3,
                                                 unsigned short* __restrict__ hfin4, int rbase) {
    int r = rbase + blockIdx.y;
    const char* xrb = (const char*)(xih + (size_t)blockIdx.y * XIH_ELEMS);   // block-uniform base
    const int* nbr = (r == 0) ? N0 : (r == 1) ? N1 : (r == 2) ? N2 : N3;
    const int* deg = (r == 0) ? D0 : (r == 1) ? D1 : (r == 2) ? D2 : D3;
    const int* order = order4 + r * 40960;
    unsigned short* hfin = hfin4 + (size_t)r * NN * FF;

    __shared__ int nodes[16];
    __shared__ int nbrs_t[17][16];             // [t][node] byte offsets; row 16 = sentinel
    __shared__ unsigned short hbuf[2][2048];   // 2 x (16 rows x 128 dims bf16), XOR-swizzled
    int tid = threadIdx.x;
    int w = tid >> 6, l = tid & 63;
    int col = l & 15, grp = l >> 4;

    // Whh slice: tiles {w+8j}, 16 frags = 64 regs
    const unsigned short* whhp = whhb + (size_t)r * NG * FF + col * FF + grp * 8;
    s16x8 breg[4][4];
#pragma unroll
    for (int j = 0; j < 4; ++j)
#pragma unroll
        for (int kt = 0; kt < 4; ++kt)
            breg[j][kt] = *(const s16x8*)(whhp + (size_t)(w + 8 * j) * 16 * FF + kt * 32);

    unsigned toff = (unsigned)((w * 64 + col * 4) * 2);   // per-lane byte offset into row

    int rbyte[4];
#pragma unroll
    for (int kt = 0; kt < 4; ++kt)
        rbyte[kt] = (col * 256 + kt * 64 + grp * 16) ^ ((col & 7) << 4);
    int wbyte[4];
#pragma unroll
    for (int q = 0; q < 4; ++q) {
        int node = grp * 4 + q;
        wbyte[q] = (node * 256 + (w * 16 + col) * 2) ^ ((node & 7) << 4);
    }

    for (int gi = 0; gi < LSTM_GROUPS; ++gi) {
        int g0 = (blockIdx.x + gi * LSTM_BLOCKS) * 16;
        __syncthreads();
        if (tid < 16) nodes[tid] = order[g0 + tid];
        __syncthreads();
        if (nodes[0] < 0) continue;          // uniform
        int degv = deg[nodes[0]];

        if (tid < 256) {
            int row = tid >> 4, t = tid & 15;   // global read stays node-coalesced
            int nd = nodes[row]; if (nd < 0) nd = 0;
            nbrs_t[t][row] = nbr[nd * DDEG + t] << 10;
        }
        if (tid < 16) nbrs_t[16][tid] = 0;      // sentinel row
        __syncthreads();

        f32x4 cst = splat4(0.f);

        u16x4 cur[4], nxt[4];
        {
            int4 of0 = *(const int4*)&nbrs_t[0][grp * 4];
            cur[0] = *(const u16x4*)(xrb + ((unsigned)of0.x + toff));
            cur[1] = *(const u16x4*)(xrb + ((unsigned)of0.y + toff));
            cur[2] = *(const u16x4*)(xrb + ((unsigned)of0.z + toff));
            cur[3] = *(const u16x4*)(xrb + ((unsigned)of0.w + toff));
        }

        for (int t = 0; t < degv; ++t) {
            {
                int4 ofn = *(const int4*)&nbrs_t[t + 1][grp * 4];   // sentinel-safe
                nxt[0] = *(const u16x4*)(xrb + ((unsigned)ofn.x + toff));
                nxt[1] = *(const u16x4*)(xrb + ((unsigned)ofn.y + toff));
                nxt[2] = *(const u16x4*)(xrb + ((unsigned)ofn.z + toff));
                nxt[3] = *(const u16x4*)(xrb + ((unsigned)ofn.w + toff));
            }
            f32x4 acc[4];
#pragma unroll
            for (int j = 0; j < 4; ++j)
#pragma unroll
                for (int q = 0; q < 4; ++q)
                    acc[j][q] = bf2f(cur[q][j]);

            if (t > 0) {
                const char* hrd = (const char*)hbuf[t & 1];
#pragma unroll
                for (int kt = 0; kt < 4; ++kt) {
                    s16x8 ah = *(const s16x8*)(hrd + rbyte[kt]);
#pragma unroll
                    for (int j = 0; j < 4; ++j)
                        acc[j] = __builtin_amdgcn_mfma_f32_16x16x32_bf16(ah, breg[j][kt], acc[j], 0, 0, 0);
                }
            }
            // exp2-domain shared-rcp activations, f32x4 arithmetic
            char* hwr = (char*)hbuf[(t + 1) & 1];
            {
                f32x4 Av, Bv, Cv, Dv;
#pragma unroll
                for (int q = 0; q < 4; ++q) {
                    Av[q] = __builtin_amdgcn_exp2f(-acc[0][q]);
                    Bv[q] = __builtin_amdgcn_exp2f(-acc[1][q]);
                    Cv[q] = __builtin_amdgcn_exp2f(acc[2][q]);
                    Dv[q] = __builtin_amdgcn_exp2f(-acc[3][q]);
                }
                f32x4 d1 = (Av + 1.0f) * (Cv + 1.0f);
                f32x4 d2 = Bv + 1.0f;
                f32x4 r1, r2;
#pragma unroll
                for (int q = 0; q < 4; ++q) {
                    r1[q] = __builtin_amdgcn_rcpf(d1[q]);
                    r2[q] = __builtin_amdgcn_rcpf(d2[q]);
                }
                f32x4 cv = cst * r2 + (Cv - 1.0f) * r1;
                cst = cv;
                f32x4 ecv = cv * TWO_L2E;
                f32x4 Ev;
#pragma unroll
                for (int q = 0; q < 4; ++q) Ev[q] = __builtin_amdgcn_exp2f(ecv[q]);
                f32x4 d3 = (Dv + 1.0f) * (Ev + 1.0f);
                f32x4 r3;
#pragma unroll
                for (int q = 0; q < 4; ++q) r3[q] = __builtin_amdgcn_rcpf(d3[q]);
                f32x4 hvv = (Ev - 1.0f) * r3;
#pragma unroll
                for (int q = 0; q < 4; ++q)
                    *(unsigned short*)(hwr + wbyte[q]) = f2bf(hvv[q]);
            }
#pragma unroll
            for (int q = 0; q < 4; ++q) cur[q] = nxt[q];
            __syncthreads();
        }
        // write h_fin from hbuf[degv & 1]: 16 rows x 256B, 8B per thread
        const char* hf = (const char*)hbuf[degv & 1];
        int row = tid >> 5;
        int nd = nodes[row];
        if (nd >= 0) {
            int off = (tid & 31) * 8;
            int byte = (row * 256 + off) ^ ((row & 7) << 4);
            u16x4 v = *(const u16x4*)(hf + byte);
            *(u16x4*)(hfin + (size_t)nd * FF + off / 2) = v;
        }
    }
}

// ---------------- projection: persistent, weights in registers --------------
#define PROJ_BLOCKS_X 160
__global__ __launch_bounds__(256, 2) void k_projh(const unsigned short* __restrict__ fbf,
                                                  const unsigned short* __restrict__ hfin4,
                                                  const unsigned short* __restrict__ wstb,
                                                  const unsigned short* __restrict__ wntb,
                                                  const float* __restrict__ bo,
                                                  const int* __restrict__ D0, const int* __restrict__ D1,
                                                  const int* __restrict__ D2, const int* __restrict__ D3,
                                                  unsigned short* __restrict__ tmp) {
    int r = blockIdx.y >> 1;
    int half = blockIdx.y & 1;
    const int* dg = (r == 0) ? D0 : (r == 1) ? D1 : (r == 2) ? D2 : D3;
    int wv = threadIdx.x >> 6, l = threadIdx.x & 63;
    int col = l & 15, grp = l >> 4;

    const unsigned short* wsb = wstb + (size_t)r * OO * FF + col * FF + grp * 8;
    const unsigned short* wnb = wntb + (size_t)r * OO * FF + col * FF + grp * 8;
    s16x8 bws[4][4], bwn[4][4];
#pragma unroll
    for (int tt = 0; tt < 4; ++tt)
#pragma unroll
        for (int kt = 0; kt < 4; ++kt) {
            size_t toff = (size_t)((half * 4 + tt) * 16) * FF + kt * 32;
            bws[tt][kt] = *(const s16x8*)(wsb + toff);
            bwn[tt][kt] = *(const s16x8*)(wnb + toff);
        }
    float bias[4];
#pragma unroll
    for (int tt = 0; tt < 4; ++tt) bias[tt] = bo[r * OO + (half * 4 + tt) * 16 + col];

    const unsigned short* hbase = hfin4 + (size_t)r * NN * FF;
    unsigned short* tp = tmp + (size_t)r * NN * OO;
    const s16x8 zfrag = {0, 0, 0, 0, 0, 0, 0, 0};

    for (int c = blockIdx.x; c < 625; c += PROJ_BLOCKS_X) {
        int n0 = c * 64 + wv * 16;
        s16x8 af[4], ah[4];
        const unsigned short* fp = fbf + (size_t)(n0 + col) * FF + grp * 8;
        const unsigned short* hp = hbase + (size_t)(n0 + col) * FF + grp * 8;
        int dval = dg[n0 + col];
#pragma unroll
        for (int kt = 0; kt < 4; ++kt) {
            af[kt] = *(const s16x8*)(fp + kt * 32);
            s16x8 h = *(const s16x8*)(hp + kt * 32);
            ah[kt] = (dval > 0) ? h : zfrag;
        }
        f32x4 acc[4];
#pragma unroll
        for (int tt = 0; tt < 4; ++tt) acc[tt] = splat4(bias[tt]);
#pragma unroll
        for (int kt = 0; kt < 4; ++kt) {
#pragma unroll
            for (int tt = 0; tt < 4; ++tt) {
                acc[tt] = __builtin_amdgcn_mfma_f32_16x16x32_bf16(af[kt], bws[tt][kt], acc[tt], 0, 0, 0);
                acc[tt] = __builtin_amdgcn_mfma_f32_16x16x32_bf16(ah[kt], bwn[tt][kt], acc[tt], 0, 0, 0);
            }
        }
#pragma unroll
        for (int q = 0; q < 4; ++q) {
            int node = n0 + grp * 4 + q;
#pragma unroll
            for (int tt = 0; tt < 4; ++tt)
                tp[node * OO + (half * 4 + tt) * 16 + col] = f2bf(acc[tt][q]);
        }
    }
}

// ---------------- combine: out = mean[seg] + max(p0,p1) + max(p2,p3) ---------
__global__ void k_combine(const unsigned short* __restrict__ tmp,
                          const float* __restrict__ mean, const int* __restrict__ seg,
                          float* __restrict__ out) {
    int i = blockIdx.x * blockDim.x + threadIdx.x;
    int idx4 = i * 4;
    if (idx4 >= NN * OO) return;
    int node = idx4 >> 7;
    int dim = idx4 & 127;
    ushort4 p0 = *(const ushort4*)(tmp + idx4);
    ushort4 p1 = *(const ushort4*)(tmp + (size_t)NN * OO + idx4);
    ushort4 p2 = *(const ushort4*)(tmp + 2 * (size_t)NN * OO + idx4);
    ushort4 p3 = *(const ushort4*)(tmp + 3 * (size_t)NN * OO + idx4);
    float4 mv = *(const float4*)(mean + seg[node] * FF + dim);
    float4 o;
    o.x = mv.x + fmaxf(bf2f(p0.x), bf2f(p1.x)) + fmaxf(bf2f(p2.x), bf2f(p3.x));
    o.y = mv.y + fmaxf(bf2f(p0.y), bf2f(p1.y)) + fmaxf(bf2f(p2.y), bf2f(p3.y));
    o.z = mv.z + fmaxf(bf2f(p0.z), bf2f(p1.z)) + fmaxf(bf2f(p2.z), bf2f(p3.z));
    o.w = mv.w + fmaxf(bf2f(p0.w), bf2f(p1.w)) + fmaxf(bf2f(p2.w), bf2f(p3.w));
    *(float4*)(out + idx4) = o;
}

extern "C" void kernel_launch(void* const* d_in, const int* in_sizes, int n_in,
                              void* d_out, int out_size, void* d_ws, size_t ws_size,
                              hipStream_t stream) {
    const float* feat = (const float*)d_in[0];
    const int* nbr[4] = {(const int*)d_in[1], (const int*)d_in[3], (const int*)d_in[5], (const int*)d_in[7]};
    const int* dgp[4] = {(const int*)d_in[2], (const int*)d_in[4], (const int*)d_in[6], (const int*)d_in[8]};
    const int* seg   = (const int*)d_in[9];
    const float* Wih = (const float*)d_in[10];
    const float* Whh = (const float*)d_in[11];
    const float* lb  = (const float*)d_in[12];
    const float* Ws  = (const float*)d_in[13];
    const float* Wn  = (const float*)d_in[14];
    const float* bo  = (const float*)d_in[15];

    char* ws = (char*)d_ws;
    float*          mean  = (float*)(ws + 0);                      //     32,768
    unsigned short* fbf   = (unsigned short*)(ws + 32768);         // 10,240,000
    unsigned short* wihb  = (unsigned short*)(ws + 10272768);      //    524,288
    unsigned short* whhb  = (unsigned short*)(ws + 10797056);      //    524,288
    unsigned short* wstb  = (unsigned short*)(ws + 11321344);      //    131,072
    unsigned short* wntb  = (unsigned short*)(ws + 11452416);      //    131,072
    unsigned short* xih   = (unsigned short*)(ws + 11583488);      // 4x or 1x 40,960,000

    const int big = (ws_size >= 217039872ULL);
    size_t xih_bytes = big ? 163840000ULL : 40960000ULL;
    unsigned short* hfin4 = (unsigned short*)(ws + 11583488 + xih_bytes);          // 40,960,000
    int*            order4= (int*)(ws + 11583488 + xih_bytes + 40960000);          //    655,360
    int*            cnt4  = (int*)(ws + 11583488 + xih_bytes + 40960000 + 655360); //      1,024
    unsigned short* tmp   = xih;   // xih dead after lstm; 40,960,000 B for 4 bf16 partials

    hipMemsetAsync(order4, 0xFF, 655360, stream);
    hipMemsetAsync(cnt4, 0, 1024, stream);

    k_prep<<<1024, 256, 0, stream>>>(Wih, Whh, Ws, Wn, feat, wihb, whhb, wstb, wntb, fbf);
    k_segmean<<<64, 512, 0, stream>>>(feat, seg, mean);
    k_count<<<dim3(157, 4), 256, 0, stream>>>(dgp[0], dgp[1], dgp[2], dgp[3], cnt4);
    k_offsets<<<1, 64, 0, stream>>>(cnt4);
    k_scatter<<<dim3(157, 4), 256, 0, stream>>>(dgp[0], dgp[1], dgp[2], dgp[3], cnt4, order4);

    if (big) {
        k_xih<<<dim3(XIH_BLOCKS_X, 4), 256, 0, stream>>>(fbf, wihb, lb, xih, 0);
        k_lstm<<<dim3(LSTM_BLOCKS, 4), 512, 0, stream>>>(xih, whhb, order4,
                                                         nbr[0], nbr[1], nbr[2], nbr[3],
                                                         dgp[0], dgp[1], dgp[2], dgp[3], hfin4, 0);
    } else {
        for (int r = 0; r < 4; ++r) {
            k_xih<<<dim3(XIH_BLOCKS_X, 1), 256, 0, stream>>>(fbf, wihb, lb, xih, r);
            k_lstm<<<dim3(LSTM_BLOCKS, 1), 512, 0, stream>>>(xih, whhb, order4,
                                                             nbr[0], nbr[1], nbr[2], nbr[3],
                                                             dgp[0], dgp[1], dgp[2], dgp[3], hfin4, r);
        }
    }
    k_projh<<<dim3(PROJ_BLOCKS_X, 8), 256, 0, stream>>>(fbf, hfin4, wstb, wntb, bo,
                                                        dgp[0], dgp[1], dgp[2], dgp[3], tmp);
    k_combine<<<5000, 256, 0, stream>>>(tmp, mean, seg, (float*)d_out);
}